// Round 12
// baseline (644.798 us; speedup 1.0000x reference)
//
#include <hip/hip_runtime.h>
#include <hip/hip_bf16.h>
#include <math.h>

#define CDIM 128
typedef unsigned short u16;
typedef unsigned int u32;
typedef short bf16x8 __attribute__((ext_vector_type(8)));
typedef float f32x4 __attribute__((ext_vector_type(4)));

// ---------- helpers ----------
__device__ __forceinline__ float bf2f(__hip_bfloat16 h) { return __bfloat162float(h); }
__device__ __forceinline__ u16 f2bfbits(float f) {
  __hip_bfloat16 h = __float2bfloat16(f);
  u16 u;
  __builtin_memcpy(&u, &h, 2);
  return u;
}
__device__ __forceinline__ float bfbits2f(u16 b) { return __uint_as_float((u32)b << 16); }
__device__ __forceinline__ float lrelu(float v) { return v > 0.f ? v : 0.2f * v; }
__device__ __forceinline__ float lo_bf(u32 v) { return __uint_as_float(v << 16); }
__device__ __forceinline__ float hi_bf(u32 v) { return __uint_as_float(v & 0xffff0000u); }
__device__ __forceinline__ u32 pack_bf(float a, float b) {
  return (u32)f2bfbits(a) | ((u32)f2bfbits(b) << 16);
}

#define WREP 8            // Wf replication factor (L2 hot-set spreading)
#define WFSZ 16384        // u16 elements per Wf copy (32 KB)

// ---------- dtype detection: flag=1 if buffer is fp32 ----------
__global__ void detect_kernel(const u16* __restrict__ p, int nwords, int* __restrict__ flag) {
  int i = blockIdx.x * blockDim.x + threadIdx.x;
  if (i >= nwords) return;
  int ex = (p[i] >> 7) & 0xFF;
  if (ex >= 0xC0) atomicOr(flag, 1);  // impossible exponent for O(1) bf16 data
}

// ---------- weight convert (any -> fp32) ----------
struct CvtJob { const void* src; float* dst; int n; };
struct CvtJobs24 { CvtJob j[24]; };
__global__ void cvt_batch_kernel(CvtJobs24 jobs, const int* __restrict__ flag) {
  CvtJob jb = jobs.j[blockIdx.y];
  int i = blockIdx.x * blockDim.x + threadIdx.x;
  if (i >= jb.n) return;
  if (*flag) jb.dst[i] = ((const float*)jb.src)[i];
  else jb.dst[i] = bf2f(((const __hip_bfloat16*)jb.src)[i]);
}

__global__ void fill_out_kernel(void* __restrict__ out, float v, int n,
                                const int* __restrict__ flag) {
  int i = blockIdx.x * blockDim.x + threadIdx.x;
  if (i >= n) return;
  if (*flag) ((float*)out)[i] = v;
  else ((__hip_bfloat16*)out)[i] = __float2bfloat16(v);
}

// ---------- weight repack fp32 -> bf16 MFMA B-fragment layout (WREP copies) ----------
struct RepackJobs { const float* src[6]; u16* dst[6]; };
__global__ void repack_w_kernel(RepackJobs jobs) {
  const float* W = jobs.src[blockIdx.y];
  u16* Wf = jobs.dst[blockIdx.y] + ((size_t)blockIdx.z << 14);
  int idx = blockIdx.x * 256 + threadIdx.x;  // 64 blocks -> 16384
  int j = idx & 7, lane = (idx >> 3) & 63, kc = (idx >> 9) & 3, nt = idx >> 11;
  int k = kc * 32 + ((lane >> 4) & 3) * 8 + j;
  int n = nt * 16 + (lane & 15);
  Wf[idx] = f2bfbits(W[k * 128 + n]);
}

// ---------- batched CSR build (8-replica histogram + rank; atomic-free fill) ----------
// R11 measured deg at 66us with WRITE 62MB vs 7MB logical: the single deg table
// ping-pongs across the 8 non-coherent per-XCD L2s (every random atomicAdd pulls
// + dirties the line on a different die -> writeback per bounce). Fix: one deg
// replica per XCD, selected by blockIdx&7 (round-robin dispatch); atomics become
// L2-local and lines have a single owner. rank[e] = within-replica rank; the
// per-node exclusive prefix over replicas (pre8) is folded into deg8 in-place
// during scanf. fill reconstructs x = (e>>10)&7 deterministically (block b of
// deg covers edges [b*1024,b*1024+1024)), so correctness never depends on the
// actual XCD mapping -- only locality does.
struct CsrJobs {
  const int* src[3]; const int* dst[3];
  int* deg8[3]; int* rank[3]; int* bsum[3]; int* offs[3]; int* adj[3];
  int Nd[3]; int E; int NM;
};
__global__ void deg_batch_kernel(CsrJobs c) {
  int y = blockIdx.y;
  int base = (blockIdx.x * blockDim.x + threadIdx.x) * 4;
  if (base >= c.E) return;
  int x = (base >> 10) & 7;           // == blockIdx.x & 7 (1024 edges per block)
  int* degy = c.deg8[y] + (size_t)x * c.NM;
  int* ranky = c.rank[y];
  const int* dsty = c.dst[y];
#pragma unroll
  for (int j = 0; j < 4; ++j) {
    int e = base + j;
    if (e < c.E) ranky[e] = atomicAdd(&degy[dsty[e]], 1);
  }
}
__global__ void scanp_batch_kernel(CsrJobs c) {
  int y = blockIdx.y, N = c.Nd[y];
  __shared__ int red[256];
  int t = threadIdx.x;
  int base = blockIdx.x * 1024 + t * 4;
  int s = 0;
#pragma unroll
  for (int j = 0; j < 4; ++j) {
    int d = base + j;
    if (d < N) {
      const int* dg = c.deg8[y] + d;
#pragma unroll
      for (int x = 0; x < 8; ++x) s += dg[(size_t)x * c.NM];
    }
  }
  red[t] = s;
  __syncthreads();
  for (int o = 128; o; o >>= 1) {
    if (t < o) red[t] += red[t + o];
    __syncthreads();
  }
  if (t == 0) c.bsum[y][blockIdx.x] = red[0];
}
__global__ void scanb_batch_kernel(CsrJobs c) {
  int y = threadIdx.x;
  if (y >= 3) return;
  int nb = (c.Nd[y] + 1023) / 1024;
  int run = 0;
  for (int i = 0; i < nb; ++i) { int v = c.bsum[y][i]; c.bsum[y][i] = run; run += v; }
  c.offs[y][c.Nd[y]] = c.E;
}
// scanf: per node, fold exclusive replica-prefix into deg8 in place; node total
// feeds the existing intra-block LDS scan that produces offs.
__global__ void scanf_batch_kernel(CsrJobs c) {
  int y = blockIdx.y, N = c.Nd[y];
  __shared__ int lds[256];
  int t = threadIdx.x;
  int base = blockIdx.x * 1024 + t * 4;
  int v[4];
#pragma unroll
  for (int j = 0; j < 4; ++j) {
    int d = base + j;
    int run = 0;
    if (d < N) {
      int* dg = c.deg8[y] + d;
#pragma unroll
      for (int x = 0; x < 8; ++x) {
        int* p = dg + (size_t)x * c.NM;
        int cnt = *p;
        *p = run;
        run += cnt;
      }
    }
    v[j] = run;
  }
  int tsum = v[0] + v[1] + v[2] + v[3];
  lds[t] = tsum;
  __syncthreads();
  for (int o = 1; o < 256; o <<= 1) {
    int x = (t >= o) ? lds[t - o] : 0;
    __syncthreads();
    lds[t] += x;
    __syncthreads();
  }
  int excl = lds[t] - tsum + c.bsum[y][blockIdx.x];
  if (base + 0 < N) c.offs[y][base + 0] = excl;
  if (base + 1 < N) c.offs[y][base + 1] = excl + v[0];
  if (base + 2 < N) c.offs[y][base + 2] = excl + v[0] + v[1];
  if (base + 3 < N) c.offs[y][base + 3] = excl + v[0] + v[1] + v[2];
}
// single-pass atomic-free fill: adj[offs[d] + pre8[x][d] + rank[e]] = src[e]
__global__ void fill_batch_kernel(CsrJobs c) {
  int y = blockIdx.y;
  int base = (blockIdx.x * blockDim.x + threadIdx.x) * 4;
  if (base >= c.E) return;
  int x = (base >> 10) & 7;           // same reconstruction as deg pass
  const int* prey = c.deg8[y] + (size_t)x * c.NM;
  const int* dsty = c.dst[y];
  const int* srcy = c.src[y];
  const int* ranky = c.rank[y];
  const int* offsy = c.offs[y];
  int* adjy = c.adj[y];
  if (base + 3 < c.E) {
    int4 d4 = *(const int4*)&dsty[base];
    int4 r4 = *(const int4*)&ranky[base];
    int4 s4 = *(const int4*)&srcy[base];
    adjy[offsy[d4.x] + prey[d4.x] + r4.x] = s4.x;
    adjy[offsy[d4.y] + prey[d4.y] + r4.y] = s4.y;
    adjy[offsy[d4.z] + prey[d4.z] + r4.z] = s4.z;
    adjy[offsy[d4.w] + prey[d4.w] + r4.w] = s4.w;
  } else {
    for (int j = 0; j < 4 && base + j < c.E; ++j) {
      int e = base + j;
      int d = dsty[e];
      adjy[offsy[d] + prey[d] + ranky[e]] = srcy[e];
    }
  }
}

// ---------- MFMA GEMM + fused per-row alpha dots (templated MODE/K) ----------
// MODE 0: bf16 X; MODE 1: raw input (fp32 if *flag); MODE 2: blend w0*X + w1*X2
struct GemmJob {
  const void* X; const void* X2; const float* W2;
  const u16* Wf; const float* bias;
  const float* av[4]; float* od[4];
  u16* out; int M;
};

template<int MODE>
__device__ __forceinline__ void gemm_load_a(
    const GemmJob& jb, const int* flag, int r, int ko, bf16x8 a[4]) {
  if (MODE == 1 && *flag) {
    const float* af = (const float*)jb.X + (size_t)r * 128 + ko;
#pragma unroll
    for (int c = 0; c < 4; ++c) {
      float4 x = *(const float4*)(af + c * 32);
      float4 y = *(const float4*)(af + c * 32 + 4);
      bf16x8 tv;
      tv[0] = (short)f2bfbits(x.x); tv[1] = (short)f2bfbits(x.y);
      tv[2] = (short)f2bfbits(x.z); tv[3] = (short)f2bfbits(x.w);
      tv[4] = (short)f2bfbits(y.x); tv[5] = (short)f2bfbits(y.y);
      tv[6] = (short)f2bfbits(y.z); tv[7] = (short)f2bfbits(y.w);
      a[c] = tv;
    }
  } else if (MODE == 2) {
    float w0 = jb.W2[0], w1 = jb.W2[1];
    const u16* g1 = (const u16*)jb.X + (size_t)r * 128 + ko;
    const u16* g2 = (const u16*)jb.X2 + (size_t)r * 128 + ko;
#pragma unroll
    for (int c = 0; c < 4; ++c) {
      bf16x8 x1 = *(const bf16x8*)(g1 + c * 32);
      bf16x8 x2 = *(const bf16x8*)(g2 + c * 32);
      bf16x8 tv;
#pragma unroll
      for (int k = 0; k < 8; ++k)
        tv[k] = (short)f2bfbits(w0 * bfbits2f((u16)x1[k]) + w1 * bfbits2f((u16)x2[k]));
      a[c] = tv;
    }
  } else {
    const u16* ab = (const u16*)jb.X + (size_t)r * 128 + ko;
#pragma unroll
    for (int c = 0; c < 4; ++c) a[c] = *(const bf16x8*)(ab + c * 32);
  }
}

template<int MODE, int K>
__global__ __launch_bounds__(256, 4) void gemm_mfma_t(
    GemmJob jb, const int* __restrict__ flag)
{
  int bx = blockIdx.x;
  int M = jb.M;
  __shared__ u16 Cs[64][136];  // 17 KB; stride 136 -> only free 2-way conflicts
  int t = threadIdx.x;
  int wave = t >> 6, lane = t & 63;
  int m = lane & 15, ko = (lane >> 4) * 8, rq = lane >> 4;
  int rowbase = bx * 128;
  const u16* wf = jb.Wf + ((size_t)(bx & (WREP - 1)) << 14);

  // both tiles' A-fragments loaded up-front: 2x loads in flight per wave
  int r0 = rowbase + wave * 16 + m;       if (r0 >= M) r0 = M - 1;
  int r1 = rowbase + 64 + wave * 16 + m;  if (r1 >= M) r1 = M - 1;
  bf16x8 a0[4], a1[4];
  gemm_load_a<MODE>(jb, flag, r0, ko, a0);
  gemm_load_a<MODE>(jb, flag, r1, ko, a1);

#pragma unroll
  for (int tile = 0; tile < 2; ++tile) {
    int row0 = rowbase + tile * 64 + wave * 16;
    bf16x8* a = tile ? a1 : a0;
    if (row0 < M) {
      f32x4 acc[8];
#pragma unroll
      for (int nt = 0; nt < 8; ++nt) acc[nt] = (f32x4){0.f, 0.f, 0.f, 0.f};
#pragma unroll
      for (int c = 0; c < 4; ++c) {
        bf16x8 b[8];
#pragma unroll
        for (int nt = 0; nt < 8; ++nt)
          b[nt] = *(const bf16x8*)(wf + ((nt * 4 + c) * 64 + lane) * 8);
#pragma unroll
        for (int nt = 0; nt < 8; ++nt)
          acc[nt] = __builtin_amdgcn_mfma_f32_16x16x32_bf16(a[c], b[nt], acc[nt], 0, 0, 0);
      }
#pragma unroll
      for (int nt = 0; nt < 8; ++nt) {
        float bv = jb.bias[nt * 16 + m];
#pragma unroll
        for (int reg = 0; reg < 4; ++reg) acc[nt][reg] += bv;
      }
#pragma unroll
      for (int nt = 0; nt < 8; ++nt) {
        int col = nt * 16 + m;
#pragma unroll
        for (int reg = 0; reg < 4; ++reg)
          Cs[wave * 16 + rq * 4 + reg][col] = f2bfbits(acc[nt][reg]);
      }
      // fused per-row alpha dots: K compile-time -> static unroll, static indexing
#pragma unroll
      for (int k = 0; k < K; ++k) {
        const float* avk = jb.av[k];
        float* odk = jb.od[k];
        float am[8];
#pragma unroll
        for (int nt = 0; nt < 8; ++nt) am[nt] = avk[nt * 16 + m];
#pragma unroll
        for (int reg = 0; reg < 4; ++reg) {
          float p0 = 0.f, p1 = 0.f;
#pragma unroll
          for (int nt = 0; nt < 4; ++nt) p0 = fmaf(acc[nt][reg], am[nt], p0);
#pragma unroll
          for (int nt = 4; nt < 8; ++nt) p1 = fmaf(acc[nt][reg], am[nt], p1);
#pragma unroll
          for (int msk = 1; msk < 16; msk <<= 1) {
            p0 += __shfl_xor(p0, msk);
            p1 += __shfl_xor(p1, msk);
          }
          if (m == 0) {
            int row = row0 + rq * 4 + reg;
            if (row < M) { odk[row * 2] = p0; odk[row * 2 + 1] = p1; }
          }
        }
      }
    }
    __syncthreads();
    // coalesced block-wide C store: 64 rows x 256B, uint4 per thread per step
#pragma unroll
    for (int kk = 0; kk < 4; ++kk) {
      int idx = t + kk * 256;
      int rowl = idx >> 4, c16 = idx & 15;
      int grow = rowbase + tile * 64 + rowl;
      if (grow < M) {
        uint4 v = *(const uint4*)&Cs[rowl][c16 * 8];
        *(uint4*)((u16*)jb.out + (size_t)grow * 128 + c16 * 8) = v;
      }
    }
    __syncthreads();
  }
}

// ---------- dual MFMA GEMM + tanh + column-sum (both metapaths in one launch) ----------
// B staged to LDS once per block; re-used across all row-tile iterations.
__global__ __launch_bounds__(256) void tanhsum_mfma_kernel(
    const u16* __restrict__ A0, const u16* __restrict__ A1,
    const u16* __restrict__ Wf, const float* __restrict__ bias,
    float* __restrict__ score, int M)
{
  const u16* A = blockIdx.y ? A1 : A0;
  float* sc = score + blockIdx.y * 128;
  __shared__ __align__(16) u16 Bs[WFSZ];
  __shared__ float sred[4][128];
  int t = threadIdx.x;
  int wave = t >> 6, lane = t & 63;
  int m = lane & 15, ko = (lane >> 4) * 8, rq = lane >> 4;
  {
    const uint4* wfg = (const uint4*)(Wf + ((size_t)(blockIdx.x & (WREP - 1)) << 14));
    uint4* bs4 = (uint4*)Bs;
#pragma unroll
    for (int i = 0; i < 8; ++i) bs4[t + i * 256] = wfg[t + i * 256];
  }
  __syncthreads();
  float colsum[8];
#pragma unroll
  for (int nt = 0; nt < 8; ++nt) colsum[nt] = 0.f;
  for (int row0 = blockIdx.x * 64 + wave * 16; row0 < M; row0 += gridDim.x * 64) {
    int r = row0 + m; if (r >= M) r = M - 1;
    const u16* arow = A + (size_t)r * 128 + ko;
    bf16x8 a[4];
#pragma unroll
    for (int c = 0; c < 4; ++c) a[c] = *(const bf16x8*)(arow + c * 32);
    f32x4 acc[8];
#pragma unroll
    for (int nt = 0; nt < 8; ++nt) acc[nt] = (f32x4){0.f, 0.f, 0.f, 0.f};
#pragma unroll
    for (int c = 0; c < 4; ++c) {
      bf16x8 b[8];
#pragma unroll
      for (int nt = 0; nt < 8; ++nt)
        b[nt] = *(const bf16x8*)(Bs + ((nt * 4 + c) * 64 + lane) * 8);
#pragma unroll
      for (int nt = 0; nt < 8; ++nt)
        acc[nt] = __builtin_amdgcn_mfma_f32_16x16x32_bf16(a[c], b[nt], acc[nt], 0, 0, 0);
    }
#pragma unroll
    for (int nt = 0; nt < 8; ++nt) {
      float bv = bias[nt * 16 + m];
#pragma unroll
      for (int reg = 0; reg < 4; ++reg) {
        int row = row0 + rq * 4 + reg;
        if (row < M) colsum[nt] += tanhf(acc[nt][reg] + bv);
      }
    }
  }
#pragma unroll
  for (int nt = 0; nt < 8; ++nt) {
    colsum[nt] += __shfl_xor(colsum[nt], 16);
    colsum[nt] += __shfl_xor(colsum[nt], 32);
  }
  if (lane < 16) {
#pragma unroll
    for (int nt = 0; nt < 8; ++nt) sred[wave][nt * 16 + lane] = colsum[nt];
  }
  __syncthreads();
  if (t < 128) {
    float tot = sred[0][t] + sred[1][t] + sred[2][t] + sred[3][t];
    atomicAdd(&sc[t], tot);
  }
}

// ---------- semantic softmax weights: W2 = softmax(q . SCORE / N) ----------
__global__ void sem_w_kernel(const float* __restrict__ score, const float* __restrict__ q,
                             float invN, float* __restrict__ W2) {
  int t = threadIdx.x;  // 64
  float s0 = 0.f, s1 = 0.f;
  for (int c = t; c < 128; c += 64) {
    float qc = q[c];
    s0 += qc * score[c];
    s1 += qc * score[128 + c];
  }
#pragma unroll
  for (int o = 32; o; o >>= 1) {
    s0 += __shfl_xor(s0, o);
    s1 += __shfl_xor(s1, o);
  }
  if (t == 0) {
    s0 *= invN; s1 *= invN;
    float mx = fmaxf(s0, s1);
    float e0 = expf(s0 - mx), e1 = expf(s1 - mx);
    float inv = 1.f / (e0 + e1);
    W2[0] = e0 * inv;
    W2[1] = e1 * inv;
  }
}

// ---------- unified per-dst softmax + gather + ReLU (packed 1-D grid) ----------
// 4 destination nodes per wave (16 lanes each, uint4 = 8 bf16 cols per lane).
// Wave-uniform fast path (__all(deg<=16)): H-row loads are issued from
// adj-only shuffles BEFORE the exp/reduce chain so HBM latency hides under the
// softmax; duplicate tail loads are exec-masked off. Mixed/large waves fall
// back to the ew-buffer path (correct for any degree).
struct GatherJob {
  const int* offs; const int* adj;
  const float* ss; const float* sd;
  float* ew;                       // per-edge exp buffer [E*2] (slow path only)
  const u16* Hs; u16* out; int Nd;
};
struct GatherJobs3 { GatherJob j[3]; };
__global__ __launch_bounds__(256) void node_gather_b_kernel(GatherJobs3 g, int nb0, int nb01)
{
  int bx = blockIdx.x;
  int jbi = bx < nb0 ? 0 : (bx < nb01 ? 1 : 2);
  int bl = jbi == 0 ? bx : (jbi == 1 ? bx - nb0 : bx - nb01);
  GatherJob jb = g.j[jbi];
  int lane = threadIdx.x & 63;
  int grp = lane >> 4, sl = lane & 15;
  int wid = bl * 4 + (threadIdx.x >> 6);
  int node = wid * 4 + grp;
  bool act = node < jb.Nd;
  int beg = 0, end = 0;
  float2 sdp = make_float2(0.f, 0.f);
  if (act) {
    beg = jb.offs[node];
    end = jb.offs[node + 1];
    sdp = ((const float2*)jb.sd)[node];
  }
  int deg = end - beg;
  const float2* ss2 = (const float2*)jb.ss;
  float2* ew2 = (float2*)jb.ew;
  const uint4* H4 = (const uint4*)jb.Hs;
  bool hi2 = sl >= 8;
  int base = grp * 16;
  float a[8];
#pragma unroll
  for (int j = 0; j < 8; ++j) a[j] = 0.f;
  float invh;
  if (__all(deg <= 16)) {
    // ---- wave-uniform fast path ----
    int adjreg = 0;
    if (sl < deg) adjreg = jb.adj[beg + sl];
    // src-row broadcasts depend only on adj -> issue H loads before softmax
    int sidx[8];
#pragma unroll
    for (int j = 0; j < 8; ++j) sidx[j] = __shfl(adjreg, base + j);
    float2 ssp = make_float2(0.f, 0.f);
    if (sl < deg) ssp = ss2[adjreg];
    uint4 v[8];
#pragma unroll
    for (int j = 0; j < 8; ++j)
      if (j < deg) v[j] = H4[(size_t)sidx[j] * 16 + sl];
    // softmax runs while H rows are in flight
    float e0r = 0.f, e1r = 0.f;
    if (sl < deg) {
      e0r = expf(lrelu(ssp.x + sdp.x));
      e1r = expf(lrelu(ssp.y + sdp.y));
    }
    float s0 = e0r, s1 = e1r;
#pragma unroll
    for (int o = 1; o < 16; o <<= 1) {
      s0 += __shfl_xor(s0, o);
      s1 += __shfl_xor(s1, o);
    }
    invh = 1.f / ((hi2 ? s1 : s0) + 1e-16f);
#pragma unroll
    for (int j = 0; j < 8; ++j) {
      float wl = __shfl(e0r, base + j);
      float wh = __shfl(e1r, base + j);
      if (j < deg) {
        float w = hi2 ? wh : wl;
        a[0] = fmaf(lo_bf(v[j].x), w, a[0]);
        a[1] = fmaf(hi_bf(v[j].x), w, a[1]);
        a[2] = fmaf(lo_bf(v[j].y), w, a[2]);
        a[3] = fmaf(hi_bf(v[j].y), w, a[3]);
        a[4] = fmaf(lo_bf(v[j].z), w, a[4]);
        a[5] = fmaf(hi_bf(v[j].z), w, a[5]);
        a[6] = fmaf(lo_bf(v[j].w), w, a[6]);
        a[7] = fmaf(hi_bf(v[j].w), w, a[7]);
      }
    }
    if (__any(deg > 8)) {   // wave-uniform second batch for deg in (8,16]
#pragma unroll
      for (int j = 0; j < 8; ++j) {
        int s2 = __shfl(adjreg, base + 8 + j);
        float wl = __shfl(e0r, base + 8 + j);
        float wh = __shfl(e1r, base + 8 + j);
        if (8 + j < deg) {
          uint4 vv = H4[(size_t)s2 * 16 + sl];
          float w = hi2 ? wh : wl;
          a[0] = fmaf(lo_bf(vv.x), w, a[0]);
          a[1] = fmaf(hi_bf(vv.x), w, a[1]);
          a[2] = fmaf(lo_bf(vv.y), w, a[2]);
          a[3] = fmaf(hi_bf(vv.y), w, a[3]);
          a[4] = fmaf(lo_bf(vv.z), w, a[4]);
          a[5] = fmaf(hi_bf(vv.z), w, a[5]);
          a[6] = fmaf(lo_bf(vv.w), w, a[6]);
          a[7] = fmaf(hi_bf(vv.w), w, a[7]);
        }
      }
    }
  } else {
    // ---- general ew-buffer path (any degree) ----
    float s0 = 0.f, s1 = 0.f;
    for (int e = beg + sl; e < end; e += 16) {
      int s = jb.adj[e];
      float2 ssp = ss2[s];
      float f0 = expf(lrelu(ssp.x + sdp.x));
      float f1 = expf(lrelu(ssp.y + sdp.y));
      ew2[e] = make_float2(f0, f1);
      s0 += f0;
      s1 += f1;
    }
#pragma unroll
    for (int o = 1; o < 16; o <<= 1) {
      s0 += __shfl_xor(s0, o);
      s1 += __shfl_xor(s1, o);
    }
    invh = 1.f / ((hi2 ? s1 : s0) + 1e-16f);
    for (int eb = beg; eb < end; eb += 4) {
      int eA[4]; uint4 v[4]; float w[4];
#pragma unroll
      for (int j = 0; j < 4; ++j) eA[j] = (eb + j < end) ? eb + j : end - 1;
#pragma unroll
      for (int j = 0; j < 4; ++j) v[j] = H4[(size_t)jb.adj[eA[j]] * 16 + sl];
#pragma unroll
      for (int j = 0; j < 4; ++j) {
        float2 p = ew2[eA[j]];
        w[j] = (eb + j < end) ? (hi2 ? p.y : p.x) : 0.f;
      }
#pragma unroll
      for (int j = 0; j < 4; ++j) {
        a[0] = fmaf(lo_bf(v[j].x), w[j], a[0]);
        a[1] = fmaf(hi_bf(v[j].x), w[j], a[1]);
        a[2] = fmaf(lo_bf(v[j].y), w[j], a[2]);
        a[3] = fmaf(hi_bf(v[j].y), w[j], a[3]);
        a[4] = fmaf(lo_bf(v[j].z), w[j], a[4]);
        a[5] = fmaf(hi_bf(v[j].z), w[j], a[5]);
        a[6] = fmaf(lo_bf(v[j].w), w[j], a[6]);
        a[7] = fmaf(hi_bf(v[j].w), w[j], a[7]);
      }
    }
  }
  if (act) {
    uint4 o;
    o.x = pack_bf(fmaxf(a[0] * invh, 0.f), fmaxf(a[1] * invh, 0.f));
    o.y = pack_bf(fmaxf(a[2] * invh, 0.f), fmaxf(a[3] * invh, 0.f));
    o.z = pack_bf(fmaxf(a[4] * invh, 0.f), fmaxf(a[5] * invh, 0.f));
    o.w = pack_bf(fmaxf(a[6] * invh, 0.f), fmaxf(a[7] * invh, 0.f));
    ((uint4*)jb.out)[(size_t)node * 16 + sl] = o;
  }
}

// ---------- weight folding, stage 1: WT1 = Wl1@Wl2 ; TB = bl1@Wl2 + bl2 ----------
__global__ void fold1_kernel(const float* __restrict__ Wl1, const float* __restrict__ bl1,
                             const float* __restrict__ Wl2, const float* __restrict__ bl2,
                             float* __restrict__ WT1, float* __restrict__ TB) {
  int idx = blockIdx.x * blockDim.x + threadIdx.x;
  if (idx < 128 * 128) {
    int m = idx >> 7, n = idx & 127;
    float acc = 0.f;
    for (int k = 0; k < 256; ++k) acc = fmaf(Wl1[m * 256 + k], Wl2[k * 128 + n], acc);
    WT1[idx] = acc;
  } else if (idx < 128 * 128 + 128) {
    int n = idx - 128 * 128;
    float acc = bl2[n];
    for (int k = 0; k < 256; ++k) acc = fmaf(bl1[k], Wl2[k * 128 + n], acc);
    TB[n] = acc;
  }
}
// ---------- weight folding, stage 2: WC = WT1@Wl3 ; BC = TB@Wl3 + bl3 ----------
__global__ void fold2_kernel(const float* __restrict__ WT1, const float* __restrict__ TB,
                             const float* __restrict__ Wl3, const float* __restrict__ bl3,
                             float* __restrict__ WC, float* __restrict__ BC) {
  int idx = blockIdx.x * blockDim.x + threadIdx.x;
  if (idx < 128 * 8) {
    int m = idx >> 3, j = idx & 7;
    float acc = 0.f;
    for (int k = 0; k < 128; ++k) acc = fmaf(WT1[m * 128 + k], Wl3[k * 8 + j], acc);
    WC[idx] = acc;
  } else if (idx < 128 * 8 + 8) {
    int j = idx - 128 * 8;
    float acc = bl3[j];
    for (int k = 0; k < 128; ++k) acc = fmaf(TB[k], Wl3[k * 8 + j], acc);
    BC[j] = acc;
  }
}

// ---------- final: out = sigmoid((w0*G1 + w1*G2) @ Wc[128x8] + bc) ----------
__global__ __launch_bounds__(256) void final_mlp_kernel(
    const u16* __restrict__ X1, const u16* __restrict__ X2,
    const float* __restrict__ W2, const int* __restrict__ flag,
    const float* __restrict__ Wc, const float* __restrict__ bc,
    void* __restrict__ out, int M) {
  __shared__ float Xs[32][130];
  int rb = blockIdx.x * 32;
  int t = threadIdx.x;
  float w0 = W2[0], w1 = W2[1];
  for (int i = t; i < 32 * 64; i += 256) {
    int r = i >> 6, c2 = i & 63;
    int gr = rb + r;
    u32 v1 = 0, v2 = 0;
    if (gr < M) {
      v1 = ((const u32*)X1)[(size_t)gr * 64 + c2];
      v2 = ((const u32*)X2)[(size_t)gr * 64 + c2];
    }
    Xs[r][c2 * 2] = w0 * lo_bf(v1) + w1 * lo_bf(v2);
    Xs[r][c2 * 2 + 1] = w0 * hi_bf(v1) + w1 * hi_bf(v2);
  }
  __syncthreads();
  int r = t >> 3, j = t & 7;
  int gr = rb + r;
  if (gr >= M) return;
  float acc = bc[j];
#pragma unroll 4
  for (int c = 0; c < 128; ++c) acc = fmaf(Xs[r][c], Wc[c * 8 + j], acc);
  float v = 1.f / (1.f + expf(-acc));
  if (*flag) ((float*)out)[(size_t)gr * 8 + j] = v;
  else ((__hip_bfloat16*)out)[(size_t)gr * 8 + j] = __float2bfloat16(v);
}

extern "C" void kernel_launch(void* const* d_in, const int* in_sizes, int n_in,
                              void* d_out, int out_size, void* d_ws, size_t ws_size,
                              hipStream_t stream) {
  const int No = in_sizes[0] / CDIM;
  const int Na = in_sizes[1] / CDIM;
  const int E = in_sizes[2] / 2;
  const int NM = No > Na ? No : Na;

  char* base = (char*)d_ws;
  size_t off = 0;
  auto alloc = [&](size_t bytes) -> void* {
    off = (off + 255) & ~(size_t)255;
    void* p = base + off;
    off += bytes;
    return p;
  };

  int* FLAG = (int*)alloc(4);
  u16* G1b = (u16*)alloc((size_t)No * CDIM * 2);
  u16* XAb = (u16*)alloc((size_t)Na * CDIM * 2);
  u16* HOb = (u16*)alloc((size_t)No * CDIM * 2);
  u16* HAb = (u16*)alloc((size_t)Na * CDIM * 2);
  u16* G2b = (u16*)alloc((size_t)No * CDIM * 2);
  float* OD0 = (float*)alloc((size_t)No * 2 * 4);
  float* OD1 = (float*)alloc((size_t)No * 2 * 4);
  float* OD2 = (float*)alloc((size_t)No * 2 * 4);
  float* OD3 = (float*)alloc((size_t)No * 2 * 4);
  float* AD0 = (float*)alloc((size_t)Na * 2 * 4);
  float* AD1 = (float*)alloc((size_t)Na * 2 * 4);
  float* EW0 = (float*)alloc((size_t)E * 2 * 4);
  float* EW1 = (float*)alloc((size_t)E * 2 * 4);
  float* EW2 = (float*)alloc((size_t)E * 2 * 4);
  int* DEG8 = (int*)alloc((size_t)NM * 3 * 8 * 4);   // 8 replicas per graph
  float* SCORE = (float*)alloc(512 * 4);   // SC layer1 = [0:256), layer2 = [256:512)
  float* SEMW = (float*)alloc(4 * 4);      // [w0,w1] layer1 ; [w0,w1] layer2
  float* WT1 = (float*)alloc(128 * 128 * 4);
  float* TB = (float*)alloc(128 * 4);
  float* WC = (float*)alloc(128 * 8 * 4);
  float* BC = (float*)alloc(8 * 4);
  int* OFFS_OO = (int*)alloc((size_t)(No + 1) * 4);
  int* OFFS_OA = (int*)alloc((size_t)(Na + 1) * 4);
  int* OFFS_AO = (int*)alloc((size_t)(No + 1) * 4);
  int* ADJ_OO = (int*)alloc((size_t)E * 4);
  int* ADJ_OA = (int*)alloc((size_t)E * 4);
  int* ADJ_AO = (int*)alloc((size_t)E * 4);
  int* RANK3 = (int*)alloc((size_t)E * 3 * 4);
  int* BSUM3 = (int*)alloc(3 * 128 * 4);
  u16* WF[6];
  for (int i = 0; i < 6; ++i) WF[i] = (u16*)alloc((size_t)WFSZ * WREP * 2);
  float* F[29];
  for (int i = 5; i < 29; ++i) F[i] = (float*)alloc((size_t)in_sizes[i] * 4);

  hipMemsetAsync(FLAG, 0, 4, stream);
  detect_kernel<<<64, 256, 0, stream>>>((const u16*)d_in[0], 16384, FLAG);

  if (off > ws_size) {
    fill_out_kernel<<<(out_size + 255) / 256, 256, 0, stream>>>(d_out, 0.25f, out_size, FLAG);
    return;
  }

  // weight converts (24 tensors -> fp32)
  {
    CvtJobs24 jobs;
    int maxn = 0;
    for (int i = 5; i < 29; ++i) {
      jobs.j[i - 5].src = d_in[i];
      jobs.j[i - 5].dst = F[i];
      jobs.j[i - 5].n = in_sizes[i];
      if (in_sizes[i] > maxn) maxn = in_sizes[i];
    }
    dim3 g((maxn + 255) / 256, 24);
    cvt_batch_kernel<<<g, 256, 0, stream>>>(jobs, FLAG);
  }

  // repack 6 weight matrices to MFMA fragment layout (WREP replicated copies)
  {
    RepackJobs rj;
    const int widx[6] = { 5, 7, 11, 14, 16, 20 };  // Wo1 Wa1 Wk1 Wo2 Wa2 Wk2
    for (int i = 0; i < 6; ++i) { rj.src[i] = F[widx[i]]; rj.dst[i] = WF[i]; }
    dim3 g(64, 6, WREP);
    repack_w_kernel<<<g, 256, 0, stream>>>(rj);
  }

  // batched CSR build (8-replica histogram + rank; atomic-free fill)
  {
    CsrJobs c;
    const int* EOO = (const int*)d_in[2];
    const int* EOA = (const int*)d_in[3];
    const int* EAO = (const int*)d_in[4];
    c.src[0] = EOO; c.dst[0] = EOO + E; c.Nd[0] = No; c.offs[0] = OFFS_OO; c.adj[0] = ADJ_OO;
    c.src[1] = EOA; c.dst[1] = EOA + E; c.Nd[1] = Na; c.offs[1] = OFFS_OA; c.adj[1] = ADJ_OA;
    c.src[2] = EAO; c.dst[2] = EAO + E; c.Nd[2] = No; c.offs[2] = OFFS_AO; c.adj[2] = ADJ_AO;
    for (int i = 0; i < 3; ++i) {
      c.deg8[i] = DEG8 + (size_t)i * NM * 8;
      c.rank[i] = RANK3 + (size_t)i * E;
      c.bsum[i] = BSUM3 + i * 128;
    }
    c.E = E;
    c.NM = NM;
    // one memset covers DEG8 + SCORE + SEMW (adjacent allocs)
    size_t zlen = (size_t)((char*)(SEMW + 4) - (char*)DEG8);
    hipMemsetAsync(DEG8, 0, zlen, stream);
    int nbmax = (NM + 1023) / 1024;
    int nbe = (E + 1023) / 1024;
    deg_batch_kernel<<<dim3(nbe, 3), 256, 0, stream>>>(c);
    scanp_batch_kernel<<<dim3(nbmax, 3), 256, 0, stream>>>(c);
    scanb_batch_kernel<<<1, 64, 0, stream>>>(c);
    scanf_batch_kernel<<<dim3(nbmax, 3), 256, 0, stream>>>(c);
    fill_batch_kernel<<<dim3(nbe, 3), 256, 0, stream>>>(c);
  }

  const int nb0 = (No + 127) / 128;
  const int nb1 = (Na + 127) / 128;

  auto run_layer = [&](int L, const void* XO, const void* XO2, const float* W2in,
                       const void* XA,
                       const float* bo, const float* ba,
                       const float* av, const float* ad, const float* bk,
                       const float* q) {
    u16* WFo = WF[L * 3 + 0];
    u16* WFa = WF[L * 3 + 1];
    u16* WFk = WF[L * 3 + 2];
    float* SC = SCORE + L * 256;
    GemmJob j0;
    j0.X = XO; j0.X2 = XO2; j0.W2 = W2in;
    j0.Wf = WFo; j0.bias = bo;
    j0.av[0] = av + 0;   j0.od[0] = OD0;
    j0.av[1] = ad + 0;   j0.od[1] = OD1;
    j0.av[2] = av + 128; j0.od[2] = OD2;
    j0.av[3] = ad + 256; j0.od[3] = OD3;
    j0.out = HOb; j0.M = No;
    GemmJob j1;
    j1.X = XA; j1.X2 = nullptr; j1.W2 = nullptr;
    j1.Wf = WFa; j1.bias = ba;
    j1.av[0] = av + 256; j1.od[0] = AD0;
    j1.av[1] = ad + 128; j1.od[1] = AD1;
    j1.av[2] = nullptr;  j1.od[2] = nullptr;
    j1.av[3] = nullptr;  j1.od[3] = nullptr;
    j1.out = HAb; j1.M = Na;
    if (L == 0) {
      gemm_mfma_t<1, 4><<<nb0, 256, 0, stream>>>(j0, FLAG);
      gemm_mfma_t<1, 2><<<nb1, 256, 0, stream>>>(j1, FLAG);
    } else {
      gemm_mfma_t<2, 4><<<nb0, 256, 0, stream>>>(j0, FLAG);
      gemm_mfma_t<0, 1><<<nb1, 256, 0, stream>>>(j1, FLAG);
    }

    GatherJobs3 ga;
    ga.j[0] = { OFFS_OO, ADJ_OO, OD0, OD1, EW0, HOb, G1b, No };
    int c0 = (No + 15) / 16, c1, c2;
    if (L == 0) {
      ga.j[1] = { OFFS_OA, ADJ_OA, OD2, AD1, EW1, HOb, XAb, Na };
      ga.j[2] = { OFFS_AO, ADJ_AO, AD0, OD3, EW2, HAb, G2b, No };
      c1 = (Na + 15) / 16;
      c2 = (No + 15) / 16;
    } else {
      ga.j[1] = { OFFS_AO, ADJ_AO, AD0, OD3, EW2, HAb, G2b, No };
      ga.j[2] = ga.j[1];
      c1 = (No + 15) / 16;
      c2 = 0;
    }
    node_gather_b_kernel<<<c0 + c1 + c2, 256, 0, stream>>>(ga, c0, c0 + c1);

    tanhsum_mfma_kernel<<<dim3(512, 2), 256, 0, stream>>>(G1b, G2b, WFk, bk, SC, No);
    sem_w_kernel<<<1, 64, 0, stream>>>(SC, q, 1.f / (float)No, SEMW + L * 2);
  };

  run_layer(0, d_in[0], nullptr, nullptr, d_in[1],
            F[6], F[8], F[9], F[10], F[12], F[13]);
  run_layer(1, G1b, G2b, SEMW, XAb,
            F[15], F[17], F[18], F[19], F[21], F[22]);

  // fold the 3 final linear layers into one 128x8 + bias (2 launches)
  fold1_kernel<<<(128 * 128 + 128 + 255) / 256, 256, 0, stream>>>(F[23], F[24], F[25], F[26], WT1, TB);
  fold2_kernel<<<(128 * 8 + 8 + 255) / 256, 256, 0, stream>>>(WT1, TB, F[27], F[28], WC, BC);

  final_mlp_kernel<<<(No + 31) / 32, 256, 0, stream>>>(G1b, G2b, SEMW + 2, FLAG, WC, BC, d_out, No);
}

// Round 13
// 598.792 us; speedup vs baseline: 1.0768x; 1.0768x over previous
//
#include <hip/hip_runtime.h>
#include <hip/hip_bf16.h>
#include <math.h>

#define CDIM 128
typedef unsigned short u16;
typedef unsigned int u32;
typedef short bf16x8 __attribute__((ext_vector_type(8)));
typedef float f32x4 __attribute__((ext_vector_type(4)));

// ---------- helpers ----------
__device__ __forceinline__ float bf2f(__hip_bfloat16 h) { return __bfloat162float(h); }
__device__ __forceinline__ u16 f2bfbits(float f) {
  __hip_bfloat16 h = __float2bfloat16(f);
  u16 u;
  __builtin_memcpy(&u, &h, 2);
  return u;
}
__device__ __forceinline__ float bfbits2f(u16 b) { return __uint_as_float((u32)b << 16); }
__device__ __forceinline__ float lrelu(float v) { return v > 0.f ? v : 0.2f * v; }
__device__ __forceinline__ float lo_bf(u32 v) { return __uint_as_float(v << 16); }
__device__ __forceinline__ float hi_bf(u32 v) { return __uint_as_float(v & 0xffff0000u); }
__device__ __forceinline__ u32 pack_bf(float a, float b) {
  return (u32)f2bfbits(a) | ((u32)f2bfbits(b) << 16);
}

#define WREP 8            // Wf replication factor (L2 hot-set spreading)
#define WFSZ 16384        // u16 elements per Wf copy (32 KB)

// ---------- dtype detection: flag=1 if buffer is fp32 ----------
__global__ void detect_kernel(const u16* __restrict__ p, int nwords, int* __restrict__ flag) {
  int i = blockIdx.x * blockDim.x + threadIdx.x;
  if (i >= nwords) return;
  int ex = (p[i] >> 7) & 0xFF;
  if (ex >= 0xC0) atomicOr(flag, 1);  // impossible exponent for O(1) bf16 data
}

// ---------- weight convert (any -> fp32) ----------
struct CvtJob { const void* src; float* dst; int n; };
struct CvtJobs24 { CvtJob j[24]; };
__global__ void cvt_batch_kernel(CvtJobs24 jobs, const int* __restrict__ flag) {
  CvtJob jb = jobs.j[blockIdx.y];
  int i = blockIdx.x * blockDim.x + threadIdx.x;
  if (i >= jb.n) return;
  if (*flag) jb.dst[i] = ((const float*)jb.src)[i];
  else jb.dst[i] = bf2f(((const __hip_bfloat16*)jb.src)[i]);
}

__global__ void fill_out_kernel(void* __restrict__ out, float v, int n,
                                const int* __restrict__ flag) {
  int i = blockIdx.x * blockDim.x + threadIdx.x;
  if (i >= n) return;
  if (*flag) ((float*)out)[i] = v;
  else ((__hip_bfloat16*)out)[i] = __float2bfloat16(v);
}

// ---------- weight repack fp32 -> bf16 MFMA B-fragment layout (WREP copies) ----------
struct RepackJobs { const float* src[6]; u16* dst[6]; };
__global__ void repack_w_kernel(RepackJobs jobs) {
  const float* W = jobs.src[blockIdx.y];
  u16* Wf = jobs.dst[blockIdx.y] + ((size_t)blockIdx.z << 14);
  int idx = blockIdx.x * 256 + threadIdx.x;  // 64 blocks -> 16384
  int j = idx & 7, lane = (idx >> 3) & 63, kc = (idx >> 9) & 3, nt = idx >> 11;
  int k = kc * 32 + ((lane >> 4) & 3) * 8 + j;
  int n = nt * 16 + (lane & 15);
  Wf[idx] = f2bfbits(W[k * 128 + n]);
}

// ---------- batched CSR build (rank-based; R11 single-table scheme) ----------
// R12 post-mortem: 8-replica deg REGRESSED (atomics-with-return write-through
// ~32B/op to HBM regardless of table layout) -> reverted to the single-table
// rank scheme. deg's remaining ~66us is idle-pipe atomic latency, which this
// round hides by CO-SCHEDULING deg blocks inside the L0 gemm launch.
struct CsrJobs {
  const int* src[3]; const int* dst[3];
  int* deg[3]; int* rank[3]; int* bsum[3]; int* offs[3]; int* adj[3];
  int Nd[3]; int E;
};
__device__ __forceinline__ void deg_body(const CsrJobs& c, int y, int bxe) {
  int base = (bxe * 256 + (int)threadIdx.x) * 4;
  if (base >= c.E) return;
  const int* dsty = c.dst[y];
  int* degy = c.deg[y];
  int* ranky = c.rank[y];
#pragma unroll
  for (int j = 0; j < 4; ++j) {
    int e = base + j;
    if (e < c.E) ranky[e] = atomicAdd(&degy[dsty[e]], 1);
  }
}
__global__ void scanp_batch_kernel(CsrJobs c) {
  int y = blockIdx.y, N = c.Nd[y];
  __shared__ int red[256];
  int t = threadIdx.x;
  int base = blockIdx.x * 1024 + t * 4;
  int s = 0;
#pragma unroll
  for (int j = 0; j < 4; ++j) if (base + j < N) s += c.deg[y][base + j];
  red[t] = s;
  __syncthreads();
  for (int o = 128; o; o >>= 1) {
    if (t < o) red[t] += red[t + o];
    __syncthreads();
  }
  if (t == 0) c.bsum[y][blockIdx.x] = red[0];
}
__global__ void scanb_batch_kernel(CsrJobs c) {
  int y = threadIdx.x;
  if (y >= 3) return;
  int nb = (c.Nd[y] + 1023) / 1024;
  int run = 0;
  for (int i = 0; i < nb; ++i) { int v = c.bsum[y][i]; c.bsum[y][i] = run; run += v; }
  c.offs[y][c.Nd[y]] = c.E;
}
__global__ void scanf_batch_kernel(CsrJobs c) {
  int y = blockIdx.y, N = c.Nd[y];
  __shared__ int lds[256];
  int t = threadIdx.x;
  int base = blockIdx.x * 1024 + t * 4;
  int v0 = (base + 0 < N) ? c.deg[y][base + 0] : 0;
  int v1 = (base + 1 < N) ? c.deg[y][base + 1] : 0;
  int v2 = (base + 2 < N) ? c.deg[y][base + 2] : 0;
  int v3 = (base + 3 < N) ? c.deg[y][base + 3] : 0;
  int tsum = v0 + v1 + v2 + v3;
  lds[t] = tsum;
  __syncthreads();
  for (int o = 1; o < 256; o <<= 1) {
    int x = (t >= o) ? lds[t - o] : 0;
    __syncthreads();
    lds[t] += x;
    __syncthreads();
  }
  int excl = lds[t] - tsum + c.bsum[y][blockIdx.x];
  if (base + 0 < N) c.offs[y][base + 0] = excl;
  if (base + 1 < N) c.offs[y][base + 1] = excl + v0;
  if (base + 2 < N) c.offs[y][base + 2] = excl + v0 + v1;
  if (base + 3 < N) c.offs[y][base + 3] = excl + v0 + v1 + v2;
}
// single-pass atomic-free fill: adj[offs[dst[e]] + rank[e]] = src[e]
__global__ void fill_batch_kernel(CsrJobs c) {
  int y = blockIdx.y;
  int base = (blockIdx.x * blockDim.x + threadIdx.x) * 4;
  if (base >= c.E) return;
  const int* dsty = c.dst[y];
  const int* srcy = c.src[y];
  const int* ranky = c.rank[y];
  const int* offsy = c.offs[y];
  int* adjy = c.adj[y];
  if (base + 3 < c.E) {
    int4 d4 = *(const int4*)&dsty[base];
    int4 r4 = *(const int4*)&ranky[base];
    int4 s4 = *(const int4*)&srcy[base];
    adjy[offsy[d4.x] + r4.x] = s4.x;
    adjy[offsy[d4.y] + r4.y] = s4.y;
    adjy[offsy[d4.z] + r4.z] = s4.z;
    adjy[offsy[d4.w] + r4.w] = s4.w;
  } else {
    for (int j = 0; j < 4 && base + j < c.E; ++j) {
      int e = base + j;
      adjy[offsy[dsty[e]] + ranky[e]] = srcy[e];
    }
  }
}

// ---------- MFMA GEMM + fused per-row alpha dots (templated MODE/K) ----------
// MODE 0: bf16 X; MODE 1: raw input (fp32 if *flag); MODE 2: blend w0*X + w1*X2
struct GemmJob {
  const void* X; const void* X2; const float* W2;
  const u16* Wf; const float* bias;
  const float* av[4]; float* od[4];
  u16* out; int M;
};

template<int MODE>
__device__ __forceinline__ void gemm_load_a(
    const GemmJob& jb, const int* flag, int r, int ko, bf16x8 a[4]) {
  if (MODE == 1 && *flag) {
    const float* af = (const float*)jb.X + (size_t)r * 128 + ko;
#pragma unroll
    for (int c = 0; c < 4; ++c) {
      float4 x = *(const float4*)(af + c * 32);
      float4 y = *(const float4*)(af + c * 32 + 4);
      bf16x8 tv;
      tv[0] = (short)f2bfbits(x.x); tv[1] = (short)f2bfbits(x.y);
      tv[2] = (short)f2bfbits(x.z); tv[3] = (short)f2bfbits(x.w);
      tv[4] = (short)f2bfbits(y.x); tv[5] = (short)f2bfbits(y.y);
      tv[6] = (short)f2bfbits(y.z); tv[7] = (short)f2bfbits(y.w);
      a[c] = tv;
    }
  } else if (MODE == 2) {
    float w0 = jb.W2[0], w1 = jb.W2[1];
    const u16* g1 = (const u16*)jb.X + (size_t)r * 128 + ko;
    const u16* g2 = (const u16*)jb.X2 + (size_t)r * 128 + ko;
#pragma unroll
    for (int c = 0; c < 4; ++c) {
      bf16x8 x1 = *(const bf16x8*)(g1 + c * 32);
      bf16x8 x2 = *(const bf16x8*)(g2 + c * 32);
      bf16x8 tv;
#pragma unroll
      for (int k = 0; k < 8; ++k)
        tv[k] = (short)f2bfbits(w0 * bfbits2f((u16)x1[k]) + w1 * bfbits2f((u16)x2[k]));
      a[c] = tv;
    }
  } else {
    const u16* ab = (const u16*)jb.X + (size_t)r * 128 + ko;
#pragma unroll
    for (int c = 0; c < 4; ++c) a[c] = *(const bf16x8*)(ab + c * 32);
  }
}

template<int MODE, int K>
__device__ __forceinline__ void gemm_body(
    const GemmJob& jb, const int* flag, int bx, u16 (*Cs)[136]) {
  int M = jb.M;
  int t = threadIdx.x;
  int wave = t >> 6, lane = t & 63;
  int m = lane & 15, ko = (lane >> 4) * 8, rq = lane >> 4;
  int rowbase = bx * 128;
  const u16* wf = jb.Wf + ((size_t)(bx & (WREP - 1)) << 14);

  // both tiles' A-fragments loaded up-front: 2x loads in flight per wave
  int r0 = rowbase + wave * 16 + m;       if (r0 >= M) r0 = M - 1;
  int r1 = rowbase + 64 + wave * 16 + m;  if (r1 >= M) r1 = M - 1;
  bf16x8 a0[4], a1[4];
  gemm_load_a<MODE>(jb, flag, r0, ko, a0);
  gemm_load_a<MODE>(jb, flag, r1, ko, a1);

#pragma unroll
  for (int tile = 0; tile < 2; ++tile) {
    int row0 = rowbase + tile * 64 + wave * 16;
    bf16x8* a = tile ? a1 : a0;
    if (row0 < M) {
      f32x4 acc[8];
#pragma unroll
      for (int nt = 0; nt < 8; ++nt) acc[nt] = (f32x4){0.f, 0.f, 0.f, 0.f};
#pragma unroll
      for (int c = 0; c < 4; ++c) {
        bf16x8 b[8];
#pragma unroll
        for (int nt = 0; nt < 8; ++nt)
          b[nt] = *(const bf16x8*)(wf + ((nt * 4 + c) * 64 + lane) * 8);
#pragma unroll
        for (int nt = 0; nt < 8; ++nt)
          acc[nt] = __builtin_amdgcn_mfma_f32_16x16x32_bf16(a[c], b[nt], acc[nt], 0, 0, 0);
      }
#pragma unroll
      for (int nt = 0; nt < 8; ++nt) {
        float bv = jb.bias[nt * 16 + m];
#pragma unroll
        for (int reg = 0; reg < 4; ++reg) acc[nt][reg] += bv;
      }
#pragma unroll
      for (int nt = 0; nt < 8; ++nt) {
        int col = nt * 16 + m;
#pragma unroll
        for (int reg = 0; reg < 4; ++reg)
          Cs[wave * 16 + rq * 4 + reg][col] = f2bfbits(acc[nt][reg]);
      }
      // fused per-row alpha dots: K compile-time -> static unroll, static indexing
#pragma unroll
      for (int k = 0; k < K; ++k) {
        const float* avk = jb.av[k];
        float* odk = jb.od[k];
        float am[8];
#pragma unroll
        for (int nt = 0; nt < 8; ++nt) am[nt] = avk[nt * 16 + m];
#pragma unroll
        for (int reg = 0; reg < 4; ++reg) {
          float p0 = 0.f, p1 = 0.f;
#pragma unroll
          for (int nt = 0; nt < 4; ++nt) p0 = fmaf(acc[nt][reg], am[nt], p0);
#pragma unroll
          for (int nt = 4; nt < 8; ++nt) p1 = fmaf(acc[nt][reg], am[nt], p1);
#pragma unroll
          for (int msk = 1; msk < 16; msk <<= 1) {
            p0 += __shfl_xor(p0, msk);
            p1 += __shfl_xor(p1, msk);
          }
          if (m == 0) {
            int row = row0 + rq * 4 + reg;
            if (row < M) { odk[row * 2] = p0; odk[row * 2 + 1] = p1; }
          }
        }
      }
    }
    __syncthreads();
    // coalesced block-wide C store: 64 rows x 256B, uint4 per thread per step
#pragma unroll
    for (int kk = 0; kk < 4; ++kk) {
      int idx = t + kk * 256;
      int rowl = idx >> 4, c16 = idx & 15;
      int grow = rowbase + tile * 64 + rowl;
      if (grow < M) {
        uint4 v = *(const uint4*)&Cs[rowl][c16 * 8];
        *(uint4*)((u16*)jb.out + (size_t)grow * 128 + c16 * 8) = v;
      }
    }
    __syncthreads();
  }
}

template<int MODE, int K>
__global__ __launch_bounds__(256, 4) void gemm_mfma_t(
    GemmJob jb, const int* __restrict__ flag)
{
  __shared__ u16 Cs[64][136];  // 17 KB; stride 136 -> only free 2-way conflicts
  gemm_body<MODE, K>(jb, flag, (int)blockIdx.x, Cs);
}

// ---------- fused L0 launch: gemm job0 + gemm job1 + CSR deg (co-scheduled) ----
// deg is ~66us of idle-pipe atomic latency; the L0 gemms don't saturate any
// pipe either. One launch with block-range dispatch lets low-resource deg
// blocks co-reside with gemm blocks on every CU, hiding the atomic round-trips
// under MFMA/load work instead of serializing behind them.
template<int M0, int K0, int M1, int K1>
__global__ __launch_bounds__(256, 4) void gemm2_deg_kernel(
    GemmJob j0, GemmJob j1, CsrJobs c, const int* __restrict__ flag,
    int nb0, int nb01, int nbe)
{
  __shared__ u16 Cs[64][136];
  int bx = blockIdx.x;
  if (bx < nb0) {
    gemm_body<M0, K0>(j0, flag, bx, Cs);
  } else if (bx < nb01) {
    gemm_body<M1, K1>(j1, flag, bx - nb0, Cs);
  } else {
    int db = bx - nb01;
    int y = db / nbe;
    deg_body(c, y, db - y * nbe);
  }
}

// ---------- dual MFMA GEMM + tanh + column-sum (both metapaths in one launch) ----------
// B staged to LDS once per block; re-used across all row-tile iterations.
__global__ __launch_bounds__(256) void tanhsum_mfma_kernel(
    const u16* __restrict__ A0, const u16* __restrict__ A1,
    const u16* __restrict__ Wf, const float* __restrict__ bias,
    float* __restrict__ score, int M)
{
  const u16* A = blockIdx.y ? A1 : A0;
  float* sc = score + blockIdx.y * 128;
  __shared__ __align__(16) u16 Bs[WFSZ];
  __shared__ float sred[4][128];
  int t = threadIdx.x;
  int wave = t >> 6, lane = t & 63;
  int m = lane & 15, ko = (lane >> 4) * 8, rq = lane >> 4;
  {
    const uint4* wfg = (const uint4*)(Wf + ((size_t)(blockIdx.x & (WREP - 1)) << 14));
    uint4* bs4 = (uint4*)Bs;
#pragma unroll
    for (int i = 0; i < 8; ++i) bs4[t + i * 256] = wfg[t + i * 256];
  }
  __syncthreads();
  float colsum[8];
#pragma unroll
  for (int nt = 0; nt < 8; ++nt) colsum[nt] = 0.f;
  for (int row0 = blockIdx.x * 64 + wave * 16; row0 < M; row0 += gridDim.x * 64) {
    int r = row0 + m; if (r >= M) r = M - 1;
    const u16* arow = A + (size_t)r * 128 + ko;
    bf16x8 a[4];
#pragma unroll
    for (int c = 0; c < 4; ++c) a[c] = *(const bf16x8*)(arow + c * 32);
    f32x4 acc[8];
#pragma unroll
    for (int nt = 0; nt < 8; ++nt) acc[nt] = (f32x4){0.f, 0.f, 0.f, 0.f};
#pragma unroll
    for (int c = 0; c < 4; ++c) {
      bf16x8 b[8];
#pragma unroll
      for (int nt = 0; nt < 8; ++nt)
        b[nt] = *(const bf16x8*)(Bs + ((nt * 4 + c) * 64 + lane) * 8);
#pragma unroll
      for (int nt = 0; nt < 8; ++nt)
        acc[nt] = __builtin_amdgcn_mfma_f32_16x16x32_bf16(a[c], b[nt], acc[nt], 0, 0, 0);
    }
#pragma unroll
    for (int nt = 0; nt < 8; ++nt) {
      float bv = bias[nt * 16 + m];
#pragma unroll
      for (int reg = 0; reg < 4; ++reg) {
        int row = row0 + rq * 4 + reg;
        if (row < M) colsum[nt] += tanhf(acc[nt][reg] + bv);
      }
    }
  }
#pragma unroll
  for (int nt = 0; nt < 8; ++nt) {
    colsum[nt] += __shfl_xor(colsum[nt], 16);
    colsum[nt] += __shfl_xor(colsum[nt], 32);
  }
  if (lane < 16) {
#pragma unroll
    for (int nt = 0; nt < 8; ++nt) sred[wave][nt * 16 + lane] = colsum[nt];
  }
  __syncthreads();
  if (t < 128) {
    float tot = sred[0][t] + sred[1][t] + sred[2][t] + sred[3][t];
    atomicAdd(&sc[t], tot);
  }
}

// ---------- semantic softmax weights: W2 = softmax(q . SCORE / N) ----------
__global__ void sem_w_kernel(const float* __restrict__ score, const float* __restrict__ q,
                             float invN, float* __restrict__ W2) {
  int t = threadIdx.x;  // 64
  float s0 = 0.f, s1 = 0.f;
  for (int c = t; c < 128; c += 64) {
    float qc = q[c];
    s0 += qc * score[c];
    s1 += qc * score[128 + c];
  }
#pragma unroll
  for (int o = 32; o; o >>= 1) {
    s0 += __shfl_xor(s0, o);
    s1 += __shfl_xor(s1, o);
  }
  if (t == 0) {
    s0 *= invN; s1 *= invN;
    float mx = fmaxf(s0, s1);
    float e0 = expf(s0 - mx), e1 = expf(s1 - mx);
    float inv = 1.f / (e0 + e1);
    W2[0] = e0 * inv;
    W2[1] = e1 * inv;
  }
}

// ---------- unified per-dst softmax + gather + ReLU (packed 1-D grid) ----------
// 4 destination nodes per wave (16 lanes each, uint4 = 8 bf16 cols per lane).
// Wave-uniform fast path (__all(deg<=16)): H-row loads are issued from
// adj-only shuffles BEFORE the exp/reduce chain so HBM latency hides under the
// softmax; duplicate tail loads are exec-masked off. Mixed/large waves fall
// back to the ew-buffer path (correct for any degree).
struct GatherJob {
  const int* offs; const int* adj;
  const float* ss; const float* sd;
  float* ew;                       // per-edge exp buffer [E*2] (slow path only)
  const u16* Hs; u16* out; int Nd;
};
struct GatherJobs3 { GatherJob j[3]; };
__global__ __launch_bounds__(256) void node_gather_b_kernel(GatherJobs3 g, int nb0, int nb01)
{
  int bx = blockIdx.x;
  int jbi = bx < nb0 ? 0 : (bx < nb01 ? 1 : 2);
  int bl = jbi == 0 ? bx : (jbi == 1 ? bx - nb0 : bx - nb01);
  GatherJob jb = g.j[jbi];
  int lane = threadIdx.x & 63;
  int grp = lane >> 4, sl = lane & 15;
  int wid = bl * 4 + (threadIdx.x >> 6);
  int node = wid * 4 + grp;
  bool act = node < jb.Nd;
  int beg = 0, end = 0;
  float2 sdp = make_float2(0.f, 0.f);
  if (act) {
    beg = jb.offs[node];
    end = jb.offs[node + 1];
    sdp = ((const float2*)jb.sd)[node];
  }
  int deg = end - beg;
  const float2* ss2 = (const float2*)jb.ss;
  float2* ew2 = (float2*)jb.ew;
  const uint4* H4 = (const uint4*)jb.Hs;
  bool hi2 = sl >= 8;
  int base = grp * 16;
  float a[8];
#pragma unroll
  for (int j = 0; j < 8; ++j) a[j] = 0.f;
  float invh;
  if (__all(deg <= 16)) {
    // ---- wave-uniform fast path ----
    int adjreg = 0;
    if (sl < deg) adjreg = jb.adj[beg + sl];
    // src-row broadcasts depend only on adj -> issue H loads before softmax
    int sidx[8];
#pragma unroll
    for (int j = 0; j < 8; ++j) sidx[j] = __shfl(adjreg, base + j);
    float2 ssp = make_float2(0.f, 0.f);
    if (sl < deg) ssp = ss2[adjreg];
    uint4 v[8];
#pragma unroll
    for (int j = 0; j < 8; ++j)
      if (j < deg) v[j] = H4[(size_t)sidx[j] * 16 + sl];
    // softmax runs while H rows are in flight
    float e0r = 0.f, e1r = 0.f;
    if (sl < deg) {
      e0r = expf(lrelu(ssp.x + sdp.x));
      e1r = expf(lrelu(ssp.y + sdp.y));
    }
    float s0 = e0r, s1 = e1r;
#pragma unroll
    for (int o = 1; o < 16; o <<= 1) {
      s0 += __shfl_xor(s0, o);
      s1 += __shfl_xor(s1, o);
    }
    invh = 1.f / ((hi2 ? s1 : s0) + 1e-16f);
#pragma unroll
    for (int j = 0; j < 8; ++j) {
      float wl = __shfl(e0r, base + j);
      float wh = __shfl(e1r, base + j);
      if (j < deg) {
        float w = hi2 ? wh : wl;
        a[0] = fmaf(lo_bf(v[j].x), w, a[0]);
        a[1] = fmaf(hi_bf(v[j].x), w, a[1]);
        a[2] = fmaf(lo_bf(v[j].y), w, a[2]);
        a[3] = fmaf(hi_bf(v[j].y), w, a[3]);
        a[4] = fmaf(lo_bf(v[j].z), w, a[4]);
        a[5] = fmaf(hi_bf(v[j].z), w, a[5]);
        a[6] = fmaf(lo_bf(v[j].w), w, a[6]);
        a[7] = fmaf(hi_bf(v[j].w), w, a[7]);
      }
    }
    if (__any(deg > 8)) {   // wave-uniform second batch for deg in (8,16]
#pragma unroll
      for (int j = 0; j < 8; ++j) {
        int s2 = __shfl(adjreg, base + 8 + j);
        float wl = __shfl(e0r, base + 8 + j);
        float wh = __shfl(e1r, base + 8 + j);
        if (8 + j < deg) {
          uint4 vv = H4[(size_t)s2 * 16 + sl];
          float w = hi2 ? wh : wl;
          a[0] = fmaf(lo_bf(vv.x), w, a[0]);
          a[1] = fmaf(hi_bf(vv.x), w, a[1]);
          a[2] = fmaf(lo_bf(vv.y), w, a[2]);
          a[3] = fmaf(hi_bf(vv.y), w, a[3]);
          a[4] = fmaf(lo_bf(vv.z), w, a[4]);
          a[5] = fmaf(hi_bf(vv.z), w, a[5]);
          a[6] = fmaf(lo_bf(vv.w), w, a[6]);
          a[7] = fmaf(hi_bf(vv.w), w, a[7]);
        }
      }
    }
  } else {
    // ---- general ew-buffer path (any degree) ----
    float s0 = 0.f, s1 = 0.f;
    for (int e = beg + sl; e < end; e += 16) {
      int s = jb.adj[e];
      float2 ssp = ss2[s];
      float f0 = expf(lrelu(ssp.x + sdp.x));
      float f1 = expf(lrelu(ssp.y + sdp.y));
      ew2[e] = make_float2(f0, f1);
      s0 += f0;
      s1 += f1;
    }
#pragma unroll
    for (int o = 1; o < 16; o <<= 1) {
      s0 += __shfl_xor(s0, o);
      s1 += __shfl_xor(s1, o);
    }
    invh = 1.f / ((hi2 ? s1 : s0) + 1e-16f);
    for (int eb = beg; eb < end; eb += 4) {
      int eA[4]; uint4 v[4]; float w[4];
#pragma unroll
      for (int j = 0; j < 4; ++j) eA[j] = (eb + j < end) ? eb + j : end - 1;
#pragma unroll
      for (int j = 0; j < 4; ++j) v[j] = H4[(size_t)jb.adj[eA[j]] * 16 + sl];
#pragma unroll
      for (int j = 0; j < 4; ++j) {
        float2 p = ew2[eA[j]];
        w[j] = (eb + j < end) ? (hi2 ? p.y : p.x) : 0.f;
      }
#pragma unroll
      for (int j = 0; j < 4; ++j) {
        a[0] = fmaf(lo_bf(v[j].x), w[j], a[0]);
        a[1] = fmaf(hi_bf(v[j].x), w[j], a[1]);
        a[2] = fmaf(lo_bf(v[j].y), w[j], a[2]);
        a[3] = fmaf(hi_bf(v[j].y), w[j], a[3]);
        a[4] = fmaf(lo_bf(v[j].z), w[j], a[4]);
        a[5] = fmaf(hi_bf(v[j].z), w[j], a[5]);
        a[6] = fmaf(lo_bf(v[j].w), w[j], a[6]);
        a[7] = fmaf(hi_bf(v[j].w), w[j], a[7]);
      }
    }
  }
  if (act) {
    uint4 o;
    o.x = pack_bf(fmaxf(a[0] * invh, 0.f), fmaxf(a[1] * invh, 0.f));
    o.y = pack_bf(fmaxf(a[2] * invh, 0.f), fmaxf(a[3] * invh, 0.f));
    o.z = pack_bf(fmaxf(a[4] * invh, 0.f), fmaxf(a[5] * invh, 0.f));
    o.w = pack_bf(fmaxf(a[6] * invh, 0.f), fmaxf(a[7] * invh, 0.f));
    ((uint4*)jb.out)[(size_t)node * 16 + sl] = o;
  }
}

// ---------- weight folding, stage 1: WT1 = Wl1@Wl2 ; TB = bl1@Wl2 + bl2 ----------
__global__ void fold1_kernel(const float* __restrict__ Wl1, const float* __restrict__ bl1,
                             const float* __restrict__ Wl2, const float* __restrict__ bl2,
                             float* __restrict__ WT1, float* __restrict__ TB) {
  int idx = blockIdx.x * blockDim.x + threadIdx.x;
  if (idx < 128 * 128) {
    int m = idx >> 7, n = idx & 127;
    float acc = 0.f;
    for (int k = 0; k < 256; ++k) acc = fmaf(Wl1[m * 256 + k], Wl2[k * 128 + n], acc);
    WT1[idx] = acc;
  } else if (idx < 128 * 128 + 128) {
    int n = idx - 128 * 128;
    float acc = bl2[n];
    for (int k = 0; k < 256; ++k) acc = fmaf(bl1[k], Wl2[k * 128 + n], acc);
    TB[n] = acc;
  }
}
// ---------- weight folding, stage 2: WC = WT1@Wl3 ; BC = TB@Wl3 + bl3 ----------
__global__ void fold2_kernel(const float* __restrict__ WT1, const float* __restrict__ TB,
                             const float* __restrict__ Wl3, const float* __restrict__ bl3,
                             float* __restrict__ WC, float* __restrict__ BC) {
  int idx = blockIdx.x * blockDim.x + threadIdx.x;
  if (idx < 128 * 8) {
    int m = idx >> 3, j = idx & 7;
    float acc = 0.f;
    for (int k = 0; k < 128; ++k) acc = fmaf(WT1[m * 128 + k], Wl3[k * 8 + j], acc);
    WC[idx] = acc;
  } else if (idx < 128 * 8 + 8) {
    int j = idx - 128 * 8;
    float acc = bl3[j];
    for (int k = 0; k < 128; ++k) acc = fmaf(TB[k], Wl3[k * 8 + j], acc);
    BC[j] = acc;
  }
}

// ---------- final: out = sigmoid((w0*G1 + w1*G2) @ Wc[128x8] + bc) ----------
__global__ __launch_bounds__(256) void final_mlp_kernel(
    const u16* __restrict__ X1, const u16* __restrict__ X2,
    const float* __restrict__ W2, const int* __restrict__ flag,
    const float* __restrict__ Wc, const float* __restrict__ bc,
    void* __restrict__ out, int M) {
  __shared__ float Xs[32][130];
  int rb = blockIdx.x * 32;
  int t = threadIdx.x;
  float w0 = W2[0], w1 = W2[1];
  for (int i = t; i < 32 * 64; i += 256) {
    int r = i >> 6, c2 = i & 63;
    int gr = rb + r;
    u32 v1 = 0, v2 = 0;
    if (gr < M) {
      v1 = ((const u32*)X1)[(size_t)gr * 64 + c2];
      v2 = ((const u32*)X2)[(size_t)gr * 64 + c2];
    }
    Xs[r][c2 * 2] = w0 * lo_bf(v1) + w1 * lo_bf(v2);
    Xs[r][c2 * 2 + 1] = w0 * hi_bf(v1) + w1 * hi_bf(v2);
  }
  __syncthreads();
  int r = t >> 3, j = t & 7;
  int gr = rb + r;
  if (gr >= M) return;
  float acc = bc[j];
#pragma unroll 4
  for (int c = 0; c < 128; ++c) acc = fmaf(Xs[r][c], Wc[c * 8 + j], acc);
  float v = 1.f / (1.f + expf(-acc));
  if (*flag) ((float*)out)[(size_t)gr * 8 + j] = v;
  else ((__hip_bfloat16*)out)[(size_t)gr * 8 + j] = __float2bfloat16(v);
}

extern "C" void kernel_launch(void* const* d_in, const int* in_sizes, int n_in,
                              void* d_out, int out_size, void* d_ws, size_t ws_size,
                              hipStream_t stream) {
  const int No = in_sizes[0] / CDIM;
  const int Na = in_sizes[1] / CDIM;
  const int E = in_sizes[2] / 2;
  const int NM = No > Na ? No : Na;

  char* base = (char*)d_ws;
  size_t off = 0;
  auto alloc = [&](size_t bytes) -> void* {
    off = (off + 255) & ~(size_t)255;
    void* p = base + off;
    off += bytes;
    return p;
  };

  int* FLAG = (int*)alloc(4);
  u16* G1b = (u16*)alloc((size_t)No * CDIM * 2);
  u16* XAb = (u16*)alloc((size_t)Na * CDIM * 2);
  u16* HOb = (u16*)alloc((size_t)No * CDIM * 2);
  u16* HAb = (u16*)alloc((size_t)Na * CDIM * 2);
  u16* G2b = (u16*)alloc((size_t)No * CDIM * 2);
  float* OD0 = (float*)alloc((size_t)No * 2 * 4);
  float* OD1 = (float*)alloc((size_t)No * 2 * 4);
  float* OD2 = (float*)alloc((size_t)No * 2 * 4);
  float* OD3 = (float*)alloc((size_t)No * 2 * 4);
  float* AD0 = (float*)alloc((size_t)Na * 2 * 4);
  float* AD1 = (float*)alloc((size_t)Na * 2 * 4);
  float* EW0 = (float*)alloc((size_t)E * 2 * 4);
  float* EW1 = (float*)alloc((size_t)E * 2 * 4);
  float* EW2 = (float*)alloc((size_t)E * 2 * 4);
  int* DEG3 = (int*)alloc((size_t)NM * 3 * 4);
  float* SCORE = (float*)alloc(512 * 4);   // SC layer1 = [0:256), layer2 = [256:512)
  float* SEMW = (float*)alloc(4 * 4);      // [w0,w1] layer1 ; [w0,w1] layer2
  float* WT1 = (float*)alloc(128 * 128 * 4);
  float* TB = (float*)alloc(128 * 4);
  float* WC = (float*)alloc(128 * 8 * 4);
  float* BC = (float*)alloc(8 * 4);
  int* OFFS_OO = (int*)alloc((size_t)(No + 1) * 4);
  int* OFFS_OA = (int*)alloc((size_t)(Na + 1) * 4);
  int* OFFS_AO = (int*)alloc((size_t)(No + 1) * 4);
  int* ADJ_OO = (int*)alloc((size_t)E * 4);
  int* ADJ_OA = (int*)alloc((size_t)E * 4);
  int* ADJ_AO = (int*)alloc((size_t)E * 4);
  int* RANK3 = (int*)alloc((size_t)E * 3 * 4);
  int* BSUM3 = (int*)alloc(3 * 128 * 4);
  u16* WF[6];
  for (int i = 0; i < 6; ++i) WF[i] = (u16*)alloc((size_t)WFSZ * WREP * 2);
  float* F[29];
  for (int i = 5; i < 29; ++i) F[i] = (float*)alloc((size_t)in_sizes[i] * 4);

  hipMemsetAsync(FLAG, 0, 4, stream);
  detect_kernel<<<64, 256, 0, stream>>>((const u16*)d_in[0], 16384, FLAG);

  if (off > ws_size) {
    fill_out_kernel<<<(out_size + 255) / 256, 256, 0, stream>>>(d_out, 0.25f, out_size, FLAG);
    return;
  }

  // weight converts (24 tensors -> fp32)
  {
    CvtJobs24 jobs;
    int maxn = 0;
    for (int i = 5; i < 29; ++i) {
      jobs.j[i - 5].src = d_in[i];
      jobs.j[i - 5].dst = F[i];
      jobs.j[i - 5].n = in_sizes[i];
      if (in_sizes[i] > maxn) maxn = in_sizes[i];
    }
    dim3 g((maxn + 255) / 256, 24);
    cvt_batch_kernel<<<g, 256, 0, stream>>>(jobs, FLAG);
  }

  // repack 6 weight matrices to MFMA fragment layout (WREP replicated copies)
  {
    RepackJobs rj;
    const int widx[6] = { 5, 7, 11, 14, 16, 20 };  // Wo1 Wa1 Wk1 Wo2 Wa2 Wk2
    for (int i = 0; i < 6; ++i) { rj.src[i] = F[widx[i]]; rj.dst[i] = WF[i]; }
    dim3 g(64, 6, WREP);
    repack_w_kernel<<<g, 256, 0, stream>>>(rj);
  }

  // CSR job descriptors (deg runs fused inside the L0 gemm launch)
  CsrJobs c;
  {
    const int* EOO = (const int*)d_in[2];
    const int* EOA = (const int*)d_in[3];
    const int* EAO = (const int*)d_in[4];
    c.src[0] = EOO; c.dst[0] = EOO + E; c.Nd[0] = No; c.offs[0] = OFFS_OO; c.adj[0] = ADJ_OO;
    c.src[1] = EOA; c.dst[1] = EOA + E; c.Nd[1] = Na; c.offs[1] = OFFS_OA; c.adj[1] = ADJ_OA;
    c.src[2] = EAO; c.dst[2] = EAO + E; c.Nd[2] = No; c.offs[2] = OFFS_AO; c.adj[2] = ADJ_AO;
    for (int i = 0; i < 3; ++i) {
      c.deg[i] = DEG3 + (size_t)i * NM;
      c.rank[i] = RANK3 + (size_t)i * E;
      c.bsum[i] = BSUM3 + i * 128;
    }
    c.E = E;
    size_t zlen = (size_t)((char*)(SEMW + 4) - (char*)DEG3);
    hipMemsetAsync(DEG3, 0, zlen, stream);
  }

  const int nb0 = (No + 127) / 128;
  const int nb1 = (Na + 127) / 128;
  const int nbmax = (NM + 1023) / 1024;
  const int nbe = (E + 1023) / 1024;

  // ---- layer 0: fused gemm(j0,j1) + deg, then CSR finish, gather, scores ----
  {
    const float* av = F[9];  const float* ad = F[10];
    GemmJob j0;
    j0.X = d_in[0]; j0.X2 = nullptr; j0.W2 = nullptr;
    j0.Wf = WF[0]; j0.bias = F[6];
    j0.av[0] = av + 0;   j0.od[0] = OD0;
    j0.av[1] = ad + 0;   j0.od[1] = OD1;
    j0.av[2] = av + 128; j0.od[2] = OD2;
    j0.av[3] = ad + 256; j0.od[3] = OD3;
    j0.out = HOb; j0.M = No;
    GemmJob j1;
    j1.X = d_in[1]; j1.X2 = nullptr; j1.W2 = nullptr;
    j1.Wf = WF[1]; j1.bias = F[8];
    j1.av[0] = av + 256; j1.od[0] = AD0;
    j1.av[1] = ad + 128; j1.od[1] = AD1;
    j1.av[2] = nullptr;  j1.od[2] = nullptr;
    j1.av[3] = nullptr;  j1.od[3] = nullptr;
    j1.out = HAb; j1.M = Na;
    gemm2_deg_kernel<1, 4, 1, 2><<<nb0 + nb1 + nbe * 3, 256, 0, stream>>>(
        j0, j1, c, FLAG, nb0, nb0 + nb1, nbe);

    scanp_batch_kernel<<<dim3(nbmax, 3), 256, 0, stream>>>(c);
    scanb_batch_kernel<<<1, 64, 0, stream>>>(c);
    scanf_batch_kernel<<<dim3(nbmax, 3), 256, 0, stream>>>(c);
    fill_batch_kernel<<<dim3(nbe, 3), 256, 0, stream>>>(c);

    GatherJobs3 ga;
    ga.j[0] = { OFFS_OO, ADJ_OO, OD0, OD1, EW0, HOb, G1b, No };
    ga.j[1] = { OFFS_OA, ADJ_OA, OD2, AD1, EW1, HOb, XAb, Na };
    ga.j[2] = { OFFS_AO, ADJ_AO, AD0, OD3, EW2, HAb, G2b, No };
    int c0 = (No + 15) / 16, c1 = (Na + 15) / 16, c2 = (No + 15) / 16;
    node_gather_b_kernel<<<c0 + c1 + c2, 256, 0, stream>>>(ga, c0, c0 + c1);

    tanhsum_mfma_kernel<<<dim3(512, 2), 256, 0, stream>>>(G1b, G2b, WF[2], F[12], SCORE, No);
    sem_w_kernel<<<1, 64, 0, stream>>>(SCORE, F[13], 1.f / (float)No, SEMW);
  }

  // ---- layer 1 ----
  {
    const float* av = F[18]; const float* ad = F[19];
    GemmJob j0;
    j0.X = G1b; j0.X2 = G2b; j0.W2 = SEMW;
    j0.Wf = WF[3]; j0.bias = F[15];
    j0.av[0] = av + 0;   j0.od[0] = OD0;
    j0.av[1] = ad + 0;   j0.od[1] = OD1;
    j0.av[2] = av + 128; j0.od[2] = OD2;
    j0.av[3] = ad + 256; j0.od[3] = OD3;
    j0.out = HOb; j0.M = No;
    GemmJob j1;
    j1.X = XAb; j1.X2 = nullptr; j1.W2 = nullptr;
    j1.Wf = WF[4]; j1.bias = F[17];
    j1.av[0] = av + 256; j1.od[0] = AD0;
    j1.av[1] = ad + 128; j1.od[1] = AD1;
    j1.av[2] = nullptr;  j1.od[2] = nullptr;
    j1.av[3] = nullptr;  j1.od[3] = nullptr;
    j1.out = HAb; j1.M = Na;
    gemm_mfma_t<2, 4><<<nb0, 256, 0, stream>>>(j0, FLAG);
    gemm_mfma_t<0, 1><<<nb1, 256, 0, stream>>>(j1, FLAG);

    GatherJobs3 ga;
    ga.j[0] = { OFFS_OO, ADJ_OO, OD0, OD1, EW0, HOb, G1b, No };
    ga.j[1] = { OFFS_AO, ADJ_AO, AD0, OD3, EW2, HAb, G2b, No };
    ga.j[2] = ga.j[1];
    int c0 = (No + 15) / 16, c1 = (No + 15) / 16;
    node_gather_b_kernel<<<c0 + c1, 256, 0, stream>>>(ga, c0, c0 + c1);

    tanhsum_mfma_kernel<<<dim3(512, 2), 256, 0, stream>>>(G1b, G2b, WF[5], F[21], SCORE + 256, No);
    sem_w_kernel<<<1, 64, 0, stream>>>(SCORE + 256, F[22], 1.f / (float)No, SEMW + 2);
  }

  // fold the 3 final linear layers into one 128x8 + bias (2 launches)
  fold1_kernel<<<(128 * 128 + 128 + 255) / 256, 256, 0, stream>>>(F[23], F[24], F[25], F[26], WT1, TB);
  fold2_kernel<<<(128 * 8 + 8 + 255) / 256, 256, 0, stream>>>(WT1, TB, F[27], F[28], WC, BC);

  final_mlp_kernel<<<(No + 31) / 32, 256, 0, stream>>>(G1b, G2b, SEMW + 2, FLAG, WC, BC, d_out, No);
}

// Round 14
// 560.679 us; speedup vs baseline: 1.1500x; 1.0680x over previous
//
#include <hip/hip_runtime.h>
#include <hip/hip_bf16.h>
#include <math.h>

#define CDIM 128
typedef unsigned short u16;
typedef unsigned int u32;
typedef short bf16x8 __attribute__((ext_vector_type(8)));
typedef float f32x4 __attribute__((ext_vector_type(4)));

// ---------- helpers ----------
__device__ __forceinline__ float bf2f(__hip_bfloat16 h) { return __bfloat162float(h); }
__device__ __forceinline__ u16 f2bfbits(float f) {
  __hip_bfloat16 h = __float2bfloat16(f);
  u16 u;
  __builtin_memcpy(&u, &h, 2);
  return u;
}
__device__ __forceinline__ float bfbits2f(u16 b) { return __uint_as_float((u32)b << 16); }
__device__ __forceinline__ float lrelu(float v) { return v > 0.f ? v : 0.2f * v; }
__device__ __forceinline__ float lo_bf(u32 v) { return __uint_as_float(v << 16); }
__device__ __forceinline__ float hi_bf(u32 v) { return __uint_as_float(v & 0xffff0000u); }
__device__ __forceinline__ u32 pack_bf(float a, float b) {
  return (u32)f2bfbits(a) | ((u32)f2bfbits(b) << 16);
}

#define WREP 8            // Wf replication factor (L2 hot-set spreading)
#define WFSZ 16384        // u16 elements per Wf copy (32 KB)

// ---------- dtype detection: flag=1 if buffer is fp32 ----------
__global__ void detect_kernel(const u16* __restrict__ p, int nwords, int* __restrict__ flag) {
  int i = blockIdx.x * blockDim.x + threadIdx.x;
  if (i >= nwords) return;
  int ex = (p[i] >> 7) & 0xFF;
  if (ex >= 0xC0) atomicOr(flag, 1);  // impossible exponent for O(1) bf16 data
}

// ---------- weight convert (any -> fp32) ----------
struct CvtJob { const void* src; float* dst; int n; };
struct CvtJobs24 { CvtJob j[24]; };
__global__ void cvt_batch_kernel(CvtJobs24 jobs, const int* __restrict__ flag) {
  CvtJob jb = jobs.j[blockIdx.y];
  int i = blockIdx.x * blockDim.x + threadIdx.x;
  if (i >= jb.n) return;
  if (*flag) jb.dst[i] = ((const float*)jb.src)[i];
  else jb.dst[i] = bf2f(((const __hip_bfloat16*)jb.src)[i]);
}

__global__ void fill_out_kernel(void* __restrict__ out, float v, int n,
                                const int* __restrict__ flag) {
  int i = blockIdx.x * blockDim.x + threadIdx.x;
  if (i >= n) return;
  if (*flag) ((float*)out)[i] = v;
  else ((__hip_bfloat16*)out)[i] = __float2bfloat16(v);
}

// ---------- weight repack fp32 -> bf16 MFMA B-fragment layout (WREP copies) ----------
struct RepackJobs { const float* src[6]; u16* dst[6]; };
__global__ void repack_w_kernel(RepackJobs jobs) {
  const float* W = jobs.src[blockIdx.y];
  u16* Wf = jobs.dst[blockIdx.y] + ((size_t)blockIdx.z << 14);
  int idx = blockIdx.x * 256 + threadIdx.x;  // 64 blocks -> 16384
  int j = idx & 7, lane = (idx >> 3) & 63, kc = (idx >> 9) & 3, nt = idx >> 11;
  int k = kc * 32 + ((lane >> 4) & 3) * 8 + j;
  int n = nt * 16 + (lane & 15);
  Wf[idx] = f2bfbits(W[k * 128 + n]);
}

// ---------- batched CSR build (rank-based; deg co-scheduled with gemm) ----------
struct CsrJobs {
  const int* src[3]; const int* dst[3];
  int* deg[3]; int* rank[3]; int* bsum[3]; int* offs[3]; int* adj[3];
  int Nd[3]; int E;
};
__device__ __forceinline__ void deg_body(const CsrJobs& c, int y, int bxe) {
  int base = (bxe * 256 + (int)threadIdx.x) * 4;
  if (base >= c.E) return;
  const int* dsty = c.dst[y];
  int* degy = c.deg[y];
  int* ranky = c.rank[y];
#pragma unroll
  for (int j = 0; j < 4; ++j) {
    int e = base + j;
    if (e < c.E) ranky[e] = atomicAdd(&degy[dsty[e]], 1);
  }
}
__global__ void scanp_batch_kernel(CsrJobs c) {
  int y = blockIdx.y, N = c.Nd[y];
  __shared__ int red[256];
  int t = threadIdx.x;
  int base = blockIdx.x * 1024 + t * 4;
  int s = 0;
#pragma unroll
  for (int j = 0; j < 4; ++j) if (base + j < N) s += c.deg[y][base + j];
  red[t] = s;
  __syncthreads();
  for (int o = 128; o; o >>= 1) {
    if (t < o) red[t] += red[t + o];
    __syncthreads();
  }
  if (t == 0) c.bsum[y][blockIdx.x] = red[0];
}
__global__ void scanb_batch_kernel(CsrJobs c) {
  int y = threadIdx.x;
  if (y >= 3) return;
  int nb = (c.Nd[y] + 1023) / 1024;
  int run = 0;
  for (int i = 0; i < nb; ++i) { int v = c.bsum[y][i]; c.bsum[y][i] = run; run += v; }
  c.offs[y][c.Nd[y]] = c.E;
}
__global__ void scanf_batch_kernel(CsrJobs c) {
  int y = blockIdx.y, N = c.Nd[y];
  __shared__ int lds[256];
  int t = threadIdx.x;
  int base = blockIdx.x * 1024 + t * 4;
  int v0 = (base + 0 < N) ? c.deg[y][base + 0] : 0;
  int v1 = (base + 1 < N) ? c.deg[y][base + 1] : 0;
  int v2 = (base + 2 < N) ? c.deg[y][base + 2] : 0;
  int v3 = (base + 3 < N) ? c.deg[y][base + 3] : 0;
  int tsum = v0 + v1 + v2 + v3;
  lds[t] = tsum;
  __syncthreads();
  for (int o = 1; o < 256; o <<= 1) {
    int x = (t >= o) ? lds[t - o] : 0;
    __syncthreads();
    lds[t] += x;
    __syncthreads();
  }
  int excl = lds[t] - tsum + c.bsum[y][blockIdx.x];
  if (base + 0 < N) c.offs[y][base + 0] = excl;
  if (base + 1 < N) c.offs[y][base + 1] = excl + v0;
  if (base + 2 < N) c.offs[y][base + 2] = excl + v0 + v1;
  if (base + 3 < N) c.offs[y][base + 3] = excl + v0 + v1 + v2;
}
// single-pass atomic-free fill: adj[offs[dst[e]] + rank[e]] = src[e]
__global__ void fill_batch_kernel(CsrJobs c) {
  int y = blockIdx.y;
  int base = (blockIdx.x * blockDim.x + threadIdx.x) * 4;
  if (base >= c.E) return;
  const int* dsty = c.dst[y];
  const int* srcy = c.src[y];
  const int* ranky = c.rank[y];
  const int* offsy = c.offs[y];
  int* adjy = c.adj[y];
  if (base + 3 < c.E) {
    int4 d4 = *(const int4*)&dsty[base];
    int4 r4 = *(const int4*)&ranky[base];
    int4 s4 = *(const int4*)&srcy[base];
    adjy[offsy[d4.x] + r4.x] = s4.x;
    adjy[offsy[d4.y] + r4.y] = s4.y;
    adjy[offsy[d4.z] + r4.z] = s4.z;
    adjy[offsy[d4.w] + r4.w] = s4.w;
  } else {
    for (int j = 0; j < 4 && base + j < c.E; ++j) {
      int e = base + j;
      adjy[offsy[dsty[e]] + ranky[e]] = srcy[e];
    }
  }
}

// ---------- MFMA GEMM + fused per-row alpha dots (templated MODE/K) ----------
// MODE 0: bf16 X; MODE 1: raw input (fp32 if *flag); MODE 2: blend w0*X + w1*X2
struct GemmJob {
  const void* X; const void* X2; const float* W2;
  const u16* Wf; const float* bias;
  const float* av[4]; float* od[4];
  u16* out; int M;
};

template<int MODE>
__device__ __forceinline__ void gemm_load_a(
    const GemmJob& jb, const int* flag, int r, int ko, bf16x8 a[4]) {
  if (MODE == 1 && *flag) {
    const float* af = (const float*)jb.X + (size_t)r * 128 + ko;
#pragma unroll
    for (int c = 0; c < 4; ++c) {
      float4 x = *(const float4*)(af + c * 32);
      float4 y = *(const float4*)(af + c * 32 + 4);
      bf16x8 tv;
      tv[0] = (short)f2bfbits(x.x); tv[1] = (short)f2bfbits(x.y);
      tv[2] = (short)f2bfbits(x.z); tv[3] = (short)f2bfbits(x.w);
      tv[4] = (short)f2bfbits(y.x); tv[5] = (short)f2bfbits(y.y);
      tv[6] = (short)f2bfbits(y.z); tv[7] = (short)f2bfbits(y.w);
      a[c] = tv;
    }
  } else if (MODE == 2) {
    float w0 = jb.W2[0], w1 = jb.W2[1];
    const u16* g1 = (const u16*)jb.X + (size_t)r * 128 + ko;
    const u16* g2 = (const u16*)jb.X2 + (size_t)r * 128 + ko;
#pragma unroll
    for (int c = 0; c < 4; ++c) {
      bf16x8 x1 = *(const bf16x8*)(g1 + c * 32);
      bf16x8 x2 = *(const bf16x8*)(g2 + c * 32);
      bf16x8 tv;
#pragma unroll
      for (int k = 0; k < 8; ++k)
        tv[k] = (short)f2bfbits(w0 * bfbits2f((u16)x1[k]) + w1 * bfbits2f((u16)x2[k]));
      a[c] = tv;
    }
  } else {
    const u16* ab = (const u16*)jb.X + (size_t)r * 128 + ko;
#pragma unroll
    for (int c = 0; c < 4; ++c) a[c] = *(const bf16x8*)(ab + c * 32);
  }
}

template<int MODE, int K>
__device__ __forceinline__ void gemm_body(
    const GemmJob& jb, const int* flag, int bx, u16 (*Cs)[136]) {
  int M = jb.M;
  int t = threadIdx.x;
  int wave = t >> 6, lane = t & 63;
  int m = lane & 15, ko = (lane >> 4) * 8, rq = lane >> 4;
  int rowbase = bx * 128;
  const u16* wf = jb.Wf + ((size_t)(bx & (WREP - 1)) << 14);

  // both tiles' A-fragments loaded up-front: 2x loads in flight per wave
  int r0 = rowbase + wave * 16 + m;       if (r0 >= M) r0 = M - 1;
  int r1 = rowbase + 64 + wave * 16 + m;  if (r1 >= M) r1 = M - 1;
  bf16x8 a0[4], a1[4];
  gemm_load_a<MODE>(jb, flag, r0, ko, a0);
  gemm_load_a<MODE>(jb, flag, r1, ko, a1);

#pragma unroll
  for (int tile = 0; tile < 2; ++tile) {
    int row0 = rowbase + tile * 64 + wave * 16;
    bf16x8* a = tile ? a1 : a0;
    if (row0 < M) {
      f32x4 acc[8];
#pragma unroll
      for (int nt = 0; nt < 8; ++nt) acc[nt] = (f32x4){0.f, 0.f, 0.f, 0.f};
#pragma unroll
      for (int c = 0; c < 4; ++c) {
        bf16x8 b[8];
#pragma unroll
        for (int nt = 0; nt < 8; ++nt)
          b[nt] = *(const bf16x8*)(wf + ((nt * 4 + c) * 64 + lane) * 8);
#pragma unroll
        for (int nt = 0; nt < 8; ++nt)
          acc[nt] = __builtin_amdgcn_mfma_f32_16x16x32_bf16(a[c], b[nt], acc[nt], 0, 0, 0);
      }
#pragma unroll
      for (int nt = 0; nt < 8; ++nt) {
        float bv = jb.bias[nt * 16 + m];
#pragma unroll
        for (int reg = 0; reg < 4; ++reg) acc[nt][reg] += bv;
      }
#pragma unroll
      for (int nt = 0; nt < 8; ++nt) {
        int col = nt * 16 + m;
#pragma unroll
        for (int reg = 0; reg < 4; ++reg)
          Cs[wave * 16 + rq * 4 + reg][col] = f2bfbits(acc[nt][reg]);
      }
      // fused per-row alpha dots: K compile-time -> static unroll, static indexing
#pragma unroll
      for (int k = 0; k < K; ++k) {
        const float* avk = jb.av[k];
        float* odk = jb.od[k];
        float am[8];
#pragma unroll
        for (int nt = 0; nt < 8; ++nt) am[nt] = avk[nt * 16 + m];
#pragma unroll
        for (int reg = 0; reg < 4; ++reg) {
          float p0 = 0.f, p1 = 0.f;
#pragma unroll
          for (int nt = 0; nt < 4; ++nt) p0 = fmaf(acc[nt][reg], am[nt], p0);
#pragma unroll
          for (int nt = 4; nt < 8; ++nt) p1 = fmaf(acc[nt][reg], am[nt], p1);
#pragma unroll
          for (int msk = 1; msk < 16; msk <<= 1) {
            p0 += __shfl_xor(p0, msk);
            p1 += __shfl_xor(p1, msk);
          }
          if (m == 0) {
            int row = row0 + rq * 4 + reg;
            if (row < M) { odk[row * 2] = p0; odk[row * 2 + 1] = p1; }
          }
        }
      }
    }
    __syncthreads();
    // coalesced block-wide C store: 64 rows x 256B, uint4 per thread per step
#pragma unroll
    for (int kk = 0; kk < 4; ++kk) {
      int idx = t + kk * 256;
      int rowl = idx >> 4, c16 = idx & 15;
      int grow = rowbase + tile * 64 + rowl;
      if (grow < M) {
        uint4 v = *(const uint4*)&Cs[rowl][c16 * 8];
        *(uint4*)((u16*)jb.out + (size_t)grow * 128 + c16 * 8) = v;
      }
    }
    __syncthreads();
  }
}

// ---------- fused launch: gemm job0 + gemm job1 + (optional) CSR deg --------
// Bresenham-interleaved block->role mapping: deg blocks are striped through
// the gemm range so low-resource (4-VGPR, atomic-latency-bound) deg blocks
// co-reside with MFMA-bound gemm blocks on every CU from cycle zero. R13's
// appended layout only overlapped in the tail (135us vs 85+66 serial);
// interleaving targets the ramp as well. ndeg==0 -> pure 2-gemm fusion
// (used for layer 1's independent gemm pair, previously 2 serial launches).
template<int M0, int K0, int M1, int K1>
__global__ __launch_bounds__(256, 4) void gemm2_deg_kernel(
    GemmJob j0, GemmJob j1, CsrJobs c, const int* __restrict__ flag,
    int nb0, int ndeg, int nbe, int NT)
{
  __shared__ u16 Cs[64][136];
  int bx = blockIdx.x;
  long lo = (long)bx * ndeg / NT;
  long hi = (long)(bx + 1) * ndeg / NT;
  if (hi > lo) {
    int db = (int)lo;
    int y = db / nbe;
    deg_body(c, y, db - y * nbe);
  } else {
    int gi = bx - (int)lo;
    if (gi < nb0) gemm_body<M0, K0>(j0, flag, gi, Cs);
    else gemm_body<M1, K1>(j1, flag, gi - nb0, Cs);
  }
}

// ---------- dual MFMA GEMM + tanh + column-sum (both metapaths in one launch) ----------
// B staged to LDS once per block; re-used across all row-tile iterations.
__global__ __launch_bounds__(256) void tanhsum_mfma_kernel(
    const u16* __restrict__ A0, const u16* __restrict__ A1,
    const u16* __restrict__ Wf, const float* __restrict__ bias,
    float* __restrict__ score, int M)
{
  const u16* A = blockIdx.y ? A1 : A0;
  float* sc = score + blockIdx.y * 128;
  __shared__ __align__(16) u16 Bs[WFSZ];
  __shared__ float sred[4][128];
  int t = threadIdx.x;
  int wave = t >> 6, lane = t & 63;
  int m = lane & 15, ko = (lane >> 4) * 8, rq = lane >> 4;
  {
    const uint4* wfg = (const uint4*)(Wf + ((size_t)(blockIdx.x & (WREP - 1)) << 14));
    uint4* bs4 = (uint4*)Bs;
#pragma unroll
    for (int i = 0; i < 8; ++i) bs4[t + i * 256] = wfg[t + i * 256];
  }
  __syncthreads();
  float colsum[8];
#pragma unroll
  for (int nt = 0; nt < 8; ++nt) colsum[nt] = 0.f;
  for (int row0 = blockIdx.x * 64 + wave * 16; row0 < M; row0 += gridDim.x * 64) {
    int r = row0 + m; if (r >= M) r = M - 1;
    const u16* arow = A + (size_t)r * 128 + ko;
    bf16x8 a[4];
#pragma unroll
    for (int c = 0; c < 4; ++c) a[c] = *(const bf16x8*)(arow + c * 32);
    f32x4 acc[8];
#pragma unroll
    for (int nt = 0; nt < 8; ++nt) acc[nt] = (f32x4){0.f, 0.f, 0.f, 0.f};
#pragma unroll
    for (int c = 0; c < 4; ++c) {
      bf16x8 b[8];
#pragma unroll
      for (int nt = 0; nt < 8; ++nt)
        b[nt] = *(const bf16x8*)(Bs + ((nt * 4 + c) * 64 + lane) * 8);
#pragma unroll
      for (int nt = 0; nt < 8; ++nt)
        acc[nt] = __builtin_amdgcn_mfma_f32_16x16x32_bf16(a[c], b[nt], acc[nt], 0, 0, 0);
    }
#pragma unroll
    for (int nt = 0; nt < 8; ++nt) {
      float bv = bias[nt * 16 + m];
#pragma unroll
      for (int reg = 0; reg < 4; ++reg) {
        int row = row0 + rq * 4 + reg;
        if (row < M) colsum[nt] += tanhf(acc[nt][reg] + bv);
      }
    }
  }
#pragma unroll
  for (int nt = 0; nt < 8; ++nt) {
    colsum[nt] += __shfl_xor(colsum[nt], 16);
    colsum[nt] += __shfl_xor(colsum[nt], 32);
  }
  if (lane < 16) {
#pragma unroll
    for (int nt = 0; nt < 8; ++nt) sred[wave][nt * 16 + lane] = colsum[nt];
  }
  __syncthreads();
  if (t < 128) {
    float tot = sred[0][t] + sred[1][t] + sred[2][t] + sred[3][t];
    atomicAdd(&sc[t], tot);
  }
}

// ---------- semantic softmax weights: W2 = softmax(q . SCORE / N) ----------
__global__ void sem_w_kernel(const float* __restrict__ score, const float* __restrict__ q,
                             float invN, float* __restrict__ W2) {
  int t = threadIdx.x;  // 64
  float s0 = 0.f, s1 = 0.f;
  for (int c = t; c < 128; c += 64) {
    float qc = q[c];
    s0 += qc * score[c];
    s1 += qc * score[128 + c];
  }
#pragma unroll
  for (int o = 32; o; o >>= 1) {
    s0 += __shfl_xor(s0, o);
    s1 += __shfl_xor(s1, o);
  }
  if (t == 0) {
    s0 *= invN; s1 *= invN;
    float mx = fmaxf(s0, s1);
    float e0 = expf(s0 - mx), e1 = expf(s1 - mx);
    float inv = 1.f / (e0 + e1);
    W2[0] = e0 * inv;
    W2[1] = e1 * inv;
  }
}

// ---------- unified per-dst softmax + gather + ReLU (packed 1-D grid) ----------
// 4 destination nodes per wave (16 lanes each, uint4 = 8 bf16 cols per lane).
// Wave-uniform fast path (__all(deg<=16)): H-row loads are issued from
// adj-only shuffles BEFORE the exp/reduce chain so HBM latency hides under the
// softmax; duplicate tail loads are exec-masked off. Mixed/large waves fall
// back to the ew-buffer path (correct for any degree).
struct GatherJob {
  const int* offs; const int* adj;
  const float* ss; const float* sd;
  float* ew;                       // per-edge exp buffer [E*2] (slow path only)
  const u16* Hs; u16* out; int Nd;
};
struct GatherJobs3 { GatherJob j[3]; };
__global__ __launch_bounds__(256) void node_gather_b_kernel(GatherJobs3 g, int nb0, int nb01)
{
  int bx = blockIdx.x;
  int jbi = bx < nb0 ? 0 : (bx < nb01 ? 1 : 2);
  int bl = jbi == 0 ? bx : (jbi == 1 ? bx - nb0 : bx - nb01);
  GatherJob jb = g.j[jbi];
  int lane = threadIdx.x & 63;
  int grp = lane >> 4, sl = lane & 15;
  int wid = bl * 4 + (threadIdx.x >> 6);
  int node = wid * 4 + grp;
  bool act = node < jb.Nd;
  int beg = 0, end = 0;
  float2 sdp = make_float2(0.f, 0.f);
  if (act) {
    beg = jb.offs[node];
    end = jb.offs[node + 1];
    sdp = ((const float2*)jb.sd)[node];
  }
  int deg = end - beg;
  const float2* ss2 = (const float2*)jb.ss;
  float2* ew2 = (float2*)jb.ew;
  const uint4* H4 = (const uint4*)jb.Hs;
  bool hi2 = sl >= 8;
  int base = grp * 16;
  float a[8];
#pragma unroll
  for (int j = 0; j < 8; ++j) a[j] = 0.f;
  float invh;
  if (__all(deg <= 16)) {
    // ---- wave-uniform fast path ----
    int adjreg = 0;
    if (sl < deg) adjreg = jb.adj[beg + sl];
    // src-row broadcasts depend only on adj -> issue H loads before softmax
    int sidx[8];
#pragma unroll
    for (int j = 0; j < 8; ++j) sidx[j] = __shfl(adjreg, base + j);
    float2 ssp = make_float2(0.f, 0.f);
    if (sl < deg) ssp = ss2[adjreg];
    uint4 v[8];
#pragma unroll
    for (int j = 0; j < 8; ++j)
      if (j < deg) v[j] = H4[(size_t)sidx[j] * 16 + sl];
    // softmax runs while H rows are in flight
    float e0r = 0.f, e1r = 0.f;
    if (sl < deg) {
      e0r = expf(lrelu(ssp.x + sdp.x));
      e1r = expf(lrelu(ssp.y + sdp.y));
    }
    float s0 = e0r, s1 = e1r;
#pragma unroll
    for (int o = 1; o < 16; o <<= 1) {
      s0 += __shfl_xor(s0, o);
      s1 += __shfl_xor(s1, o);
    }
    invh = 1.f / ((hi2 ? s1 : s0) + 1e-16f);
#pragma unroll
    for (int j = 0; j < 8; ++j) {
      float wl = __shfl(e0r, base + j);
      float wh = __shfl(e1r, base + j);
      if (j < deg) {
        float w = hi2 ? wh : wl;
        a[0] = fmaf(lo_bf(v[j].x), w, a[0]);
        a[1] = fmaf(hi_bf(v[j].x), w, a[1]);
        a[2] = fmaf(lo_bf(v[j].y), w, a[2]);
        a[3] = fmaf(hi_bf(v[j].y), w, a[3]);
        a[4] = fmaf(lo_bf(v[j].z), w, a[4]);
        a[5] = fmaf(hi_bf(v[j].z), w, a[5]);
        a[6] = fmaf(lo_bf(v[j].w), w, a[6]);
        a[7] = fmaf(hi_bf(v[j].w), w, a[7]);
      }
    }
    if (__any(deg > 8)) {   // wave-uniform second batch for deg in (8,16]
#pragma unroll
      for (int j = 0; j < 8; ++j) {
        int s2 = __shfl(adjreg, base + 8 + j);
        float wl = __shfl(e0r, base + 8 + j);
        float wh = __shfl(e1r, base + 8 + j);
        if (8 + j < deg) {
          uint4 vv = H4[(size_t)s2 * 16 + sl];
          float w = hi2 ? wh : wl;
          a[0] = fmaf(lo_bf(vv.x), w, a[0]);
          a[1] = fmaf(hi_bf(vv.x), w, a[1]);
          a[2] = fmaf(lo_bf(vv.y), w, a[2]);
          a[3] = fmaf(hi_bf(vv.y), w, a[3]);
          a[4] = fmaf(lo_bf(vv.z), w, a[4]);
          a[5] = fmaf(hi_bf(vv.z), w, a[5]);
          a[6] = fmaf(lo_bf(vv.w), w, a[6]);
          a[7] = fmaf(hi_bf(vv.w), w, a[7]);
        }
      }
    }
  } else {
    // ---- general ew-buffer path (any degree) ----
    float s0 = 0.f, s1 = 0.f;
    for (int e = beg + sl; e < end; e += 16) {
      int s = jb.adj[e];
      float2 ssp = ss2[s];
      float f0 = expf(lrelu(ssp.x + sdp.x));
      float f1 = expf(lrelu(ssp.y + sdp.y));
      ew2[e] = make_float2(f0, f1);
      s0 += f0;
      s1 += f1;
    }
#pragma unroll
    for (int o = 1; o < 16; o <<= 1) {
      s0 += __shfl_xor(s0, o);
      s1 += __shfl_xor(s1, o);
    }
    invh = 1.f / ((hi2 ? s1 : s0) + 1e-16f);
    for (int eb = beg; eb < end; eb += 4) {
      int eA[4]; uint4 v[4]; float w[4];
#pragma unroll
      for (int j = 0; j < 4; ++j) eA[j] = (eb + j < end) ? eb + j : end - 1;
#pragma unroll
      for (int j = 0; j < 4; ++j) v[j] = H4[(size_t)jb.adj[eA[j]] * 16 + sl];
#pragma unroll
      for (int j = 0; j < 4; ++j) {
        float2 p = ew2[eA[j]];
        w[j] = (eb + j < end) ? (hi2 ? p.y : p.x) : 0.f;
      }
#pragma unroll
      for (int j = 0; j < 4; ++j) {
        a[0] = fmaf(lo_bf(v[j].x), w[j], a[0]);
        a[1] = fmaf(hi_bf(v[j].x), w[j], a[1]);
        a[2] = fmaf(lo_bf(v[j].y), w[j], a[2]);
        a[3] = fmaf(hi_bf(v[j].y), w[j], a[3]);
        a[4] = fmaf(lo_bf(v[j].z), w[j], a[4]);
        a[5] = fmaf(hi_bf(v[j].z), w[j], a[5]);
        a[6] = fmaf(lo_bf(v[j].w), w[j], a[6]);
        a[7] = fmaf(hi_bf(v[j].w), w[j], a[7]);
      }
    }
  }
  if (act) {
    uint4 o;
    o.x = pack_bf(fmaxf(a[0] * invh, 0.f), fmaxf(a[1] * invh, 0.f));
    o.y = pack_bf(fmaxf(a[2] * invh, 0.f), fmaxf(a[3] * invh, 0.f));
    o.z = pack_bf(fmaxf(a[4] * invh, 0.f), fmaxf(a[5] * invh, 0.f));
    o.w = pack_bf(fmaxf(a[6] * invh, 0.f), fmaxf(a[7] * invh, 0.f));
    ((uint4*)jb.out)[(size_t)node * 16 + sl] = o;
  }
}

// ---------- weight folding, stage 1: WT1 = Wl1@Wl2 ; TB = bl1@Wl2 + bl2 ----------
__global__ void fold1_kernel(const float* __restrict__ Wl1, const float* __restrict__ bl1,
                             const float* __restrict__ Wl2, const float* __restrict__ bl2,
                             float* __restrict__ WT1, float* __restrict__ TB) {
  int idx = blockIdx.x * blockDim.x + threadIdx.x;
  if (idx < 128 * 128) {
    int m = idx >> 7, n = idx & 127;
    float acc = 0.f;
    for (int k = 0; k < 256; ++k) acc = fmaf(Wl1[m * 256 + k], Wl2[k * 128 + n], acc);
    WT1[idx] = acc;
  } else if (idx < 128 * 128 + 128) {
    int n = idx - 128 * 128;
    float acc = bl2[n];
    for (int k = 0; k < 256; ++k) acc = fmaf(bl1[k], Wl2[k * 128 + n], acc);
    TB[n] = acc;
  }
}
// ---------- weight folding, stage 2: WC = WT1@Wl3 ; BC = TB@Wl3 + bl3 ----------
__global__ void fold2_kernel(const float* __restrict__ WT1, const float* __restrict__ TB,
                             const float* __restrict__ Wl3, const float* __restrict__ bl3,
                             float* __restrict__ WC, float* __restrict__ BC) {
  int idx = blockIdx.x * blockDim.x + threadIdx.x;
  if (idx < 128 * 8) {
    int m = idx >> 3, j = idx & 7;
    float acc = 0.f;
    for (int k = 0; k < 128; ++k) acc = fmaf(WT1[m * 128 + k], Wl3[k * 8 + j], acc);
    WC[idx] = acc;
  } else if (idx < 128 * 8 + 8) {
    int j = idx - 128 * 8;
    float acc = bl3[j];
    for (int k = 0; k < 128; ++k) acc = fmaf(TB[k], Wl3[k * 8 + j], acc);
    BC[j] = acc;
  }
}

// ---------- final: out = sigmoid((w0*G1 + w1*G2) @ Wc[128x8] + bc) ----------
__global__ __launch_bounds__(256) void final_mlp_kernel(
    const u16* __restrict__ X1, const u16* __restrict__ X2,
    const float* __restrict__ W2, const int* __restrict__ flag,
    const float* __restrict__ Wc, const float* __restrict__ bc,
    void* __restrict__ out, int M) {
  __shared__ float Xs[32][130];
  int rb = blockIdx.x * 32;
  int t = threadIdx.x;
  float w0 = W2[0], w1 = W2[1];
  for (int i = t; i < 32 * 64; i += 256) {
    int r = i >> 6, c2 = i & 63;
    int gr = rb + r;
    u32 v1 = 0, v2 = 0;
    if (gr < M) {
      v1 = ((const u32*)X1)[(size_t)gr * 64 + c2];
      v2 = ((const u32*)X2)[(size_t)gr * 64 + c2];
    }
    Xs[r][c2 * 2] = w0 * lo_bf(v1) + w1 * lo_bf(v2);
    Xs[r][c2 * 2 + 1] = w0 * hi_bf(v1) + w1 * hi_bf(v2);
  }
  __syncthreads();
  int r = t >> 3, j = t & 7;
  int gr = rb + r;
  if (gr >= M) return;
  float acc = bc[j];
#pragma unroll 4
  for (int c = 0; c < 128; ++c) acc = fmaf(Xs[r][c], Wc[c * 8 + j], acc);
  float v = 1.f / (1.f + expf(-acc));
  if (*flag) ((float*)out)[(size_t)gr * 8 + j] = v;
  else ((__hip_bfloat16*)out)[(size_t)gr * 8 + j] = __float2bfloat16(v);
}

extern "C" void kernel_launch(void* const* d_in, const int* in_sizes, int n_in,
                              void* d_out, int out_size, void* d_ws, size_t ws_size,
                              hipStream_t stream) {
  const int No = in_sizes[0] / CDIM;
  const int Na = in_sizes[1] / CDIM;
  const int E = in_sizes[2] / 2;
  const int NM = No > Na ? No : Na;

  char* base = (char*)d_ws;
  size_t off = 0;
  auto alloc = [&](size_t bytes) -> void* {
    off = (off + 255) & ~(size_t)255;
    void* p = base + off;
    off += bytes;
    return p;
  };

  int* FLAG = (int*)alloc(4);
  u16* G1b = (u16*)alloc((size_t)No * CDIM * 2);
  u16* XAb = (u16*)alloc((size_t)Na * CDIM * 2);
  u16* HOb = (u16*)alloc((size_t)No * CDIM * 2);
  u16* HAb = (u16*)alloc((size_t)Na * CDIM * 2);
  u16* G2b = (u16*)alloc((size_t)No * CDIM * 2);
  float* OD0 = (float*)alloc((size_t)No * 2 * 4);
  float* OD1 = (float*)alloc((size_t)No * 2 * 4);
  float* OD2 = (float*)alloc((size_t)No * 2 * 4);
  float* OD3 = (float*)alloc((size_t)No * 2 * 4);
  float* AD0 = (float*)alloc((size_t)Na * 2 * 4);
  float* AD1 = (float*)alloc((size_t)Na * 2 * 4);
  float* EW0 = (float*)alloc((size_t)E * 2 * 4);
  float* EW1 = (float*)alloc((size_t)E * 2 * 4);
  float* EW2 = (float*)alloc((size_t)E * 2 * 4);
  int* DEG3 = (int*)alloc((size_t)NM * 3 * 4);
  float* SCORE = (float*)alloc(512 * 4);   // SC layer1 = [0:256), layer2 = [256:512)
  float* SEMW = (float*)alloc(4 * 4);      // [w0,w1] layer1 ; [w0,w1] layer2
  float* WT1 = (float*)alloc(128 * 128 * 4);
  float* TB = (float*)alloc(128 * 4);
  float* WC = (float*)alloc(128 * 8 * 4);
  float* BC = (float*)alloc(8 * 4);
  int* OFFS_OO = (int*)alloc((size_t)(No + 1) * 4);
  int* OFFS_OA = (int*)alloc((size_t)(Na + 1) * 4);
  int* OFFS_AO = (int*)alloc((size_t)(No + 1) * 4);
  int* ADJ_OO = (int*)alloc((size_t)E * 4);
  int* ADJ_OA = (int*)alloc((size_t)E * 4);
  int* ADJ_AO = (int*)alloc((size_t)E * 4);
  int* RANK3 = (int*)alloc((size_t)E * 3 * 4);
  int* BSUM3 = (int*)alloc(3 * 128 * 4);
  u16* WF[6];
  for (int i = 0; i < 6; ++i) WF[i] = (u16*)alloc((size_t)WFSZ * WREP * 2);
  float* F[29];
  for (int i = 5; i < 29; ++i) F[i] = (float*)alloc((size_t)in_sizes[i] * 4);

  hipMemsetAsync(FLAG, 0, 4, stream);
  detect_kernel<<<64, 256, 0, stream>>>((const u16*)d_in[0], 16384, FLAG);

  if (off > ws_size) {
    fill_out_kernel<<<(out_size + 255) / 256, 256, 0, stream>>>(d_out, 0.25f, out_size, FLAG);
    return;
  }

  // weight converts (24 tensors -> fp32)
  {
    CvtJobs24 jobs;
    int maxn = 0;
    for (int i = 5; i < 29; ++i) {
      jobs.j[i - 5].src = d_in[i];
      jobs.j[i - 5].dst = F[i];
      jobs.j[i - 5].n = in_sizes[i];
      if (in_sizes[i] > maxn) maxn = in_sizes[i];
    }
    dim3 g((maxn + 255) / 256, 24);
    cvt_batch_kernel<<<g, 256, 0, stream>>>(jobs, FLAG);
  }

  // repack 6 weight matrices to MFMA fragment layout (WREP replicated copies)
  {
    RepackJobs rj;
    const int widx[6] = { 5, 7, 11, 14, 16, 20 };  // Wo1 Wa1 Wk1 Wo2 Wa2 Wk2
    for (int i = 0; i < 6; ++i) { rj.src[i] = F[widx[i]]; rj.dst[i] = WF[i]; }
    dim3 g(64, 6, WREP);
    repack_w_kernel<<<g, 256, 0, stream>>>(rj);
  }

  // CSR job descriptors (deg runs fused inside the L0 gemm launch)
  CsrJobs c;
  {
    const int* EOO = (const int*)d_in[2];
    const int* EOA = (const int*)d_in[3];
    const int* EAO = (const int*)d_in[4];
    c.src[0] = EOO; c.dst[0] = EOO + E; c.Nd[0] = No; c.offs[0] = OFFS_OO; c.adj[0] = ADJ_OO;
    c.src[1] = EOA; c.dst[1] = EOA + E; c.Nd[1] = Na; c.offs[1] = OFFS_OA; c.adj[1] = ADJ_OA;
    c.src[2] = EAO; c.dst[2] = EAO + E; c.Nd[2] = No; c.offs[2] = OFFS_AO; c.adj[2] = ADJ_AO;
    for (int i = 0; i < 3; ++i) {
      c.deg[i] = DEG3 + (size_t)i * NM;
      c.rank[i] = RANK3 + (size_t)i * E;
      c.bsum[i] = BSUM3 + i * 128;
    }
    c.E = E;
    size_t zlen = (size_t)((char*)(SEMW + 4) - (char*)DEG3);
    hipMemsetAsync(DEG3, 0, zlen, stream);
  }

  const int nb0 = (No + 127) / 128;
  const int nb1 = (Na + 127) / 128;
  const int nbmax = (NM + 1023) / 1024;
  const int nbe = (E + 1023) / 1024;

  // ---- layer 0: fused gemm(j0,j1) + interleaved deg; CSR finish; gather ----
  {
    const float* av = F[9];  const float* ad = F[10];
    GemmJob j0;
    j0.X = d_in[0]; j0.X2 = nullptr; j0.W2 = nullptr;
    j0.Wf = WF[0]; j0.bias = F[6];
    j0.av[0] = av + 0;   j0.od[0] = OD0;
    j0.av[1] = ad + 0;   j0.od[1] = OD1;
    j0.av[2] = av + 128; j0.od[2] = OD2;
    j0.av[3] = ad + 256; j0.od[3] = OD3;
    j0.out = HOb; j0.M = No;
    GemmJob j1;
    j1.X = d_in[1]; j1.X2 = nullptr; j1.W2 = nullptr;
    j1.Wf = WF[1]; j1.bias = F[8];
    j1.av[0] = av + 256; j1.od[0] = AD0;
    j1.av[1] = ad + 128; j1.od[1] = AD1;
    j1.av[2] = nullptr;  j1.od[2] = nullptr;
    j1.av[3] = nullptr;  j1.od[3] = nullptr;
    j1.out = HAb; j1.M = Na;
    int ndeg = nbe * 3;
    int NT = nb0 + nb1 + ndeg;
    gemm2_deg_kernel<1, 4, 1, 2><<<NT, 256, 0, stream>>>(
        j0, j1, c, FLAG, nb0, ndeg, nbe, NT);

    scanp_batch_kernel<<<dim3(nbmax, 3), 256, 0, stream>>>(c);
    scanb_batch_kernel<<<1, 64, 0, stream>>>(c);
    scanf_batch_kernel<<<dim3(nbmax, 3), 256, 0, stream>>>(c);
    fill_batch_kernel<<<dim3(nbe, 3), 256, 0, stream>>>(c);

    GatherJobs3 ga;
    ga.j[0] = { OFFS_OO, ADJ_OO, OD0, OD1, EW0, HOb, G1b, No };
    ga.j[1] = { OFFS_OA, ADJ_OA, OD2, AD1, EW1, HOb, XAb, Na };
    ga.j[2] = { OFFS_AO, ADJ_AO, AD0, OD3, EW2, HAb, G2b, No };
    int c0 = (No + 15) / 16, c1 = (Na + 15) / 16, c2 = (No + 15) / 16;
    node_gather_b_kernel<<<c0 + c1 + c2, 256, 0, stream>>>(ga, c0, c0 + c1);

    tanhsum_mfma_kernel<<<dim3(512, 2), 256, 0, stream>>>(G1b, G2b, WF[2], F[12], SCORE, No);
    sem_w_kernel<<<1, 64, 0, stream>>>(SCORE, F[13], 1.f / (float)No, SEMW);
  }

  // ---- layer 1: fused gemm pair (ndeg=0 path), gather, scores ----
  {
    const float* av = F[18]; const float* ad = F[19];
    GemmJob j0;
    j0.X = G1b; j0.X2 = G2b; j0.W2 = SEMW;
    j0.Wf = WF[3]; j0.bias = F[15];
    j0.av[0] = av + 0;   j0.od[0] = OD0;
    j0.av[1] = ad + 0;   j0.od[1] = OD1;
    j0.av[2] = av + 128; j0.od[2] = OD2;
    j0.av[3] = ad + 256; j0.od[3] = OD3;
    j0.out = HOb; j0.M = No;
    GemmJob j1;
    j1.X = XAb; j1.X2 = nullptr; j1.W2 = nullptr;
    j1.Wf = WF[4]; j1.bias = F[17];
    j1.av[0] = av + 256; j1.od[0] = AD0;
    j1.av[1] = ad + 128; j1.od[1] = AD1;
    j1.av[2] = nullptr;  j1.od[2] = nullptr;
    j1.av[3] = nullptr;  j1.od[3] = nullptr;
    j1.out = HAb; j1.M = Na;
    int NT = nb0 + nb1;
    gemm2_deg_kernel<2, 4, 0, 1><<<NT, 256, 0, stream>>>(
        j0, j1, c, FLAG, nb0, 0, 1, NT);

    GatherJobs3 ga;
    ga.j[0] = { OFFS_OO, ADJ_OO, OD0, OD1, EW0, HOb, G1b, No };
    ga.j[1] = { OFFS_AO, ADJ_AO, AD0, OD3, EW2, HAb, G2b, No };
    ga.j[2] = ga.j[1];
    int c0 = (No + 15) / 16, c1 = (No + 15) / 16;
    node_gather_b_kernel<<<c0 + c1, 256, 0, stream>>>(ga, c0, c0 + c1);

    tanhsum_mfma_kernel<<<dim3(512, 2), 256, 0, stream>>>(G1b, G2b, WF[5], F[21], SCORE + 256, No);
    sem_w_kernel<<<1, 64, 0, stream>>>(SCORE + 256, F[22], 1.f / (float)No, SEMW + 2);
  }

  // fold the 3 final linear layers into one 128x8 + bias (2 launches)
  fold1_kernel<<<(128 * 128 + 128 + 255) / 256, 256, 0, stream>>>(F[23], F[24], F[25], F[26], WT1, TB);
  fold2_kernel<<<(128 * 8 + 8 + 255) / 256, 256, 0, stream>>>(WT1, TB, F[27], F[28], WC, BC);

  final_mlp_kernel<<<(No + 31) / 32, 256, 0, stream>>>(G1b, G2b, SEMW + 2, FLAG, WC, BC, d_out, No);
}